// Round 14
// baseline (837.346 us; speedup 1.0000x reference)
//
#include <hip/hip_runtime.h>
#include <hip/hip_bf16.h>
#include <math.h>

// DistributedAFNO2D: out = x + irfft2( blockMLP( rfft2(x, ortho) ), ortho )
// B=2, C=768, H=W=256, 8 blocks x 96 ch, KW = 129 frequency cols.
// F in d_ws: bf16-packed complex (u32 = [imag:bf16 | real:bf16]), layout (B*C, KW, H).
// Passes: rowfft -> [fused: colFFT + MFMA mix + inv colFFT] -> rowifft.
// colmix: 512 thr / 128 VGPRs; chain twiddles (phase A) + LDS twiddle table
// (phase C); DPP/swizzle lane exchanges; phase-A global prefetch; GEMM bf-pair
// split (round 14) to keep live pressure ~112 < 128 (kills residual spills).
// rowfft: row-pair input prefetch (round 14).

#define LAMBDA_SS 0.01f

typedef unsigned int u32;
typedef __attribute__((ext_vector_type(8))) short bf16x8;
typedef __attribute__((ext_vector_type(4))) float f32x4;

__device__ __forceinline__ u32 pack_bf16(float r, float i) {
  union { float f; u32 u; } ur, ui;
  ur.f = r; ui.f = i;
  u32 rb = (ur.u + 0x7FFFu + ((ur.u >> 16) & 1u)) >> 16;
  u32 ib = (ui.u + 0x7FFFu + ((ui.u >> 16) & 1u)) >> 16;
  return (ib << 16) | (rb & 0xFFFFu);
}

__device__ __forceinline__ float2 unpack_bf16(u32 p) {
  union { u32 u; float f; } a, b;
  a.u = (p & 0xFFFFu) << 16;
  b.u = (p & 0xFFFF0000u);
  return make_float2(a.f, b.f);
}

__device__ __forceinline__ float sshrink(float v) {
  return (v > LAMBDA_SS) ? v - LAMBDA_SS : ((v < -LAMBDA_SS) ? v + LAMBDA_SS : 0.f);
}

// ---------------- register FFT machinery (shared helpers) ----------------
__device__ __forceinline__ float2 cadd(float2 a, float2 b){ return make_float2(a.x+b.x, a.y+b.y); }
__device__ __forceinline__ float2 csub(float2 a, float2 b){ return make_float2(a.x-b.x, a.y-b.y); }
__device__ __forceinline__ float2 cmul(float2 a, float2 b){
  return make_float2(fmaf(a.x,b.x,-a.y*b.y), fmaf(a.x,b.y,a.y*b.x));
}
__device__ __forceinline__ float2 cmulj(float2 a, float si){  // a * (si*i)
  return make_float2(-si*a.y, si*a.x);
}
__device__ __forceinline__ float2 shflx(float2 v, int m){
  return make_float2(__shfl_xor(v.x, m, 64), __shfl_xor(v.y, m, 64));
}
__device__ __forceinline__ float2 shfll(float2 v, int l){
  return make_float2(__shfl(v.x, l, 64), __shfl(v.y, l, 64));
}
__device__ __forceinline__ int brev6(int x){ return (int)(__brev((u32)x) >> 26); }

// lane exchange by XOR mask M: DPP for 1/2, ds_swizzle for 4/8/16, shfl for 32
template<int M>
__device__ __forceinline__ float xl(float x){
  if constexpr (M == 32) {
    return __shfl_xor(x, 32, 64);
  } else if constexpr (M >= 4) {
    return __int_as_float(__builtin_amdgcn_ds_swizzle(__float_as_int(x), (M << 10) | 0x1F));
  } else {
    constexpr int ctrl = (M == 2) ? 0x4E : 0xB1;   // quad_perm [2,3,0,1] / [1,0,3,2]
    return __int_as_float(__builtin_amdgcn_update_dpp(0, __float_as_int(x), ctrl, 0xF, 0xF, true));
  }
}
template<int M>
__device__ __forceinline__ float2 xch2(float2 v){ return make_float2(xl<M>(v.x), xl<M>(v.y)); }

// ======== layout A: d = lane + 64r (row kernels) ========
struct Tw { float2 t128, t64, t32, t16, t8, t4; float si; };

__device__ __forceinline__ float2 mkTw(int e, float si){
  float a = (float)e * 0.0245436926f;   // 2*pi/256
  return make_float2(cosf(a), si*sinf(a));
}
__device__ __forceinline__ Tw make_tw(int lane, float si){
  Tw w; w.si = si;
  w.t128 = mkTw(lane, si);
  w.t64  = mkTw(2*lane, si);
  w.t32  = mkTw((lane&31)*4, si);
  w.t16  = mkTw((lane&15)*8, si);
  w.t8   = mkTw((lane&7)*16, si);
  w.t4   = mkTw((lane&3)*32, si);
  return w;
}

__device__ __forceinline__ float2 bfly_dif(float2 v, int h, float2 th, int lane){
  float2 p = shflx(v, h);
  float sx = (lane & h) ? -1.f : 1.f;
  float2 s = make_float2(fmaf(sx, v.x, p.x), fmaf(sx, v.y, p.y));
  if (lane & h) s = cmul(s, th);
  return s;
}
__device__ __forceinline__ float2 bfly_dit(float2 v, int h, float2 th, int lane){
  if (lane & h) v = cmul(v, th);
  float2 p = shflx(v, h);
  float sx = (lane & h) ? -1.f : 1.f;
  return make_float2(fmaf(sx, v.x, p.x), fmaf(sx, v.y, p.y));
}

__device__ __forceinline__ void fft256_dif(float2 v[4], int lane, const Tw& T){
  float2 t128b = cmulj(T.t128, T.si);
  { float2 a=v[0], b=v[2]; v[0]=cadd(a,b); v[2]=cmul(csub(a,b), T.t128);
    float2 c=v[1], d=v[3]; v[1]=cadd(c,d); v[3]=cmul(csub(c,d), t128b); }
  { float2 a=v[0], b=v[1]; v[0]=cadd(a,b); v[1]=cmul(csub(a,b), T.t64);
    float2 c=v[2], d=v[3]; v[2]=cadd(c,d); v[3]=cmul(csub(c,d), T.t64); }
#pragma unroll
  for (int r=0;r<4;++r) v[r]=bfly_dif(v[r],32,T.t32,lane);
#pragma unroll
  for (int r=0;r<4;++r) v[r]=bfly_dif(v[r],16,T.t16,lane);
#pragma unroll
  for (int r=0;r<4;++r) v[r]=bfly_dif(v[r],8,T.t8,lane);
#pragma unroll
  for (int r=0;r<4;++r) v[r]=bfly_dif(v[r],4,T.t4,lane);
#pragma unroll
  for (int r=0;r<4;++r){
    float2 p=shflx(v[r],2);
    float sx=(lane&2)?-1.f:1.f;
    float2 s=make_float2(fmaf(sx,v[r].x,p.x), fmaf(sx,v[r].y,p.y));
    if ((lane&3)==3) s=cmulj(s,T.si);
    v[r]=s;
  }
#pragma unroll
  for (int r=0;r<4;++r){
    float2 p=shflx(v[r],1);
    float sx=(lane&1)?-1.f:1.f;
    v[r]=make_float2(fmaf(sx,v[r].x,p.x), fmaf(sx,v[r].y,p.y));
  }
}

__device__ __forceinline__ void fft256_dit(float2 v[4], int lane, const Tw& T){
#pragma unroll
  for (int r=0;r<4;++r){
    float2 p=shflx(v[r],1);
    float sx=(lane&1)?-1.f:1.f;
    v[r]=make_float2(fmaf(sx,v[r].x,p.x), fmaf(sx,v[r].y,p.y));
  }
#pragma unroll
  for (int r=0;r<4;++r){
    float2 w=v[r];
    if ((lane&3)==3) w=cmulj(w,T.si);
    float2 p=shflx(w,2);
    float sx=(lane&2)?-1.f:1.f;
    v[r]=make_float2(fmaf(sx,w.x,p.x), fmaf(sx,w.y,p.y));
  }
#pragma unroll
  for (int r=0;r<4;++r) v[r]=bfly_dit(v[r],4,T.t4,lane);
#pragma unroll
  for (int r=0;r<4;++r) v[r]=bfly_dit(v[r],8,T.t8,lane);
#pragma unroll
  for (int r=0;r<4;++r) v[r]=bfly_dit(v[r],16,T.t16,lane);
#pragma unroll
  for (int r=0;r<4;++r) v[r]=bfly_dit(v[r],32,T.t32,lane);
  { v[1]=cmul(v[1],T.t64); float2 a=v[0]; v[0]=cadd(a,v[1]); v[1]=csub(a,v[1]);
    v[3]=cmul(v[3],T.t64); float2 c=v[2]; v[2]=cadd(c,v[3]); v[3]=csub(c,v[3]); }
  { v[2]=cmul(v[2],T.t128); v[3]=cmul(v[3], cmulj(T.t128,T.si));
    float2 a=v[0]; v[0]=cadd(a,v[2]); v[2]=csub(a,v[2]);
    float2 b=v[1]; v[1]=cadd(b,v[3]); v[3]=csub(b,v[3]); }
}

// ======== layout B: d = 4*lane + r (colmix; chain twiddles + LDS table) ========
template<int M>
__device__ __forceinline__ void difA_stage(float2 v4[4][4], const float2 tw[4], int lane){
#pragma unroll
  for (int r=0;r<4;++r){
#pragma unroll
    for (int cc=0;cc<4;++cc){
      float2 p = xch2<M>(v4[cc][r]);
      float sx = (lane & M) ? -1.f : 1.f;
      float2 t = make_float2(fmaf(sx, v4[cc][r].x, p.x), fmaf(sx, v4[cc][r].y, p.y));
      float2 tm = cmul(t, tw[r]);
      v4[cc][r] = (lane & M) ? tm : t;
    }
  }
}
template<int M>
__device__ __forceinline__ void ditC_stage(float2 v4[4][4], const float2 tw[4], int lane){
#pragma unroll
  for (int r=0;r<4;++r){
#pragma unroll
    for (int cc=0;cc<4;++cc){
      float2 w = v4[cc][r];
      float2 wm_ = make_float2(fmaf(w.x, tw[r].x,  w.y*tw[r].y),
                               fmaf(w.y, tw[r].x, -w.x*tw[r].y));
      float2 u = (lane & M) ? wm_ : w;
      float2 p = xch2<M>(u);
      float sx = (lane & M) ? -1.f : 1.f;
      v4[cc][r] = make_float2(fmaf(sx, u.x, p.x), fmaf(sx, u.y, p.y));
    }
  }
}
__device__ __forceinline__ void tw_advance(float2 tw[4], int e[4]){
#pragma unroll
  for (int r=0;r<4;++r){
    float2 sq = cmul(tw[r], tw[r]);
    if (e[r] & 64) { sq.x = -sq.x; sq.y = -sq.y; }
    e[r] = (2*e[r]) & 127;
    tw[r] = sq;
  }
}

__device__ __forceinline__ int stage_row(int kw){ return 33*(kw&3) + (kw>>2); }
__device__ __forceinline__ int dslot(int n){ return (((n>>2)&7) ^ ((n&3)<<1)) << 4; }

// ---------------- Pass 1: row rfft, 2 real rows per complex FFT ----------------
__global__ __launch_bounds__(256) void k_rowfft(const float* __restrict__ x, u32* __restrict__ F) {
  __shared__ u32 stage[131*65];
  const int bc = blockIdx.x >> 2, hc = blockIdx.x & 3;
  const int tid = threadIdx.x, wave = tid >> 6, lane = tid & 63;
  Tw T = make_tw(lane, -1.f);
  const int L = brev6(lane);
  const int laneP0 = brev6((64 - L) & 63);
  const int lanePX = 63 - lane;

  float cx0[4], cx1[4];
  {
    const float* xa = x + ((size_t)bc*256 + hc*64 + wave*16) * 256;
#pragma unroll
    for (int r=0;r<4;++r){ cx0[r]=xa[lane+64*r]; cx1[r]=xa[256+lane+64*r]; }
  }
#pragma unroll
  for (int rr = 0; rr < 8; ++rr) {
    const int hl0 = wave*16 + rr*2, hl1 = hl0 + 1;
    float nx0[4], nx1[4];
    if (rr < 7) {
      const float* xb = x + ((size_t)bc*256 + hc*64 + hl0 + 2) * 256;
#pragma unroll
      for (int r=0;r<4;++r){ nx0[r]=xb[lane+64*r]; nx1[r]=xb[256+lane+64*r]; }
    }
    float2 v[4];
#pragma unroll
    for (int r=0;r<4;++r) v[r] = make_float2(cx0[r], cx1[r]);
    fft256_dif(v, lane, T);
#define UNSCR(R, RP, C, LP) { \
      float2 z = v[R]; float2 p = shfll(v[RP], LP); \
      float2 A  = make_float2(0.5f*(z.x+p.x), 0.5f*(z.y-p.y)); \
      float2 Bv = make_float2(0.5f*(z.y+p.y), 0.5f*(p.x-z.x)); \
      int kw = 4*L + (C); \
      if (kw <= 128) { int row = stage_row(kw); \
        stage[row*65 + hl0] = pack_bf16(A.x, A.y); \
        stage[row*65 + hl1] = pack_bf16(Bv.x, Bv.y); } }
    UNSCR(0, 0, 0, laneP0)
    UNSCR(1, 1, 2, lanePX)
    UNSCR(2, 3, 1, lanePX)
    UNSCR(3, 2, 3, lanePX)
#undef UNSCR
    if (rr < 7) {
#pragma unroll
      for (int r=0;r<4;++r){ cx0[r]=nx0[r]; cx1[r]=nx1[r]; }
    }
  }
  __syncthreads();
  for (int idx = tid; idx < 129*64; idx += 256) {
    int kw = idx >> 6, hl = idx & 63;
    F[((size_t)bc*129 + kw)*256 + hc*64 + hl] = stage[stage_row(kw)*65 + hl];
  }
}

// ---------------- Weight prep ----------------
__global__ __launch_bounds__(256) void k_prep_w(const float2* __restrict__ w1,
                                                const float2* __restrict__ w2,
                                                u32* __restrict__ Wt) {
  const int blk = blockIdx.x;      // k*2 + layer
  const int k = blk >> 1, layer = blk & 1;
  const float2* w = (layer == 0 ? w1 : w2) + (size_t)k * 96 * 96;
  u32* out = Wt + (size_t)blk * 18432;
  for (int idx = threadIdx.x; idx < 9216; idx += 256) {
    int o = idx % 96, i = idx / 96;
    float2 v = w[i * 96 + o];
    out[(2 * o) * 96 + i]     = pack_bf16(v.x, -v.y);
    out[(2 * o + 1) * 96 + i] = pack_bf16(v.y, v.x);
  }
}

// ---------------- Fused pass: colFFT + MFMA mix + inv colFFT, per (b,k,kw) -------
// 512 thr / 8 waves (2 wm x 4 wn). LDS (111360 B):
//   [0, 98304):      Dlds[n=0..255][kk=0..191] bf16, byte = n*384 + kk*2 ^ dslot(n)
//   [0, 99072):      Clds[c=0..95][n] u32 (phase C staging; overlaps Dlds)
//   [99072, 111360): Tlds[24][64] float2 forward twiddles (s*4+r major, lane minor)
#define CM_LDS_BYTES 111360
#define TLDS_OFF     99072

__global__ __launch_bounds__(512, 2) void k_colmix(u32* __restrict__ F,
    const u32* __restrict__ Wt,
    const float2* __restrict__ b1, const float2* __restrict__ b2) {
  extern __shared__ char smem[];
  float2* Tlds = reinterpret_cast<float2*>(smem + TLDS_OFF);

  const int bi = (blockIdx.x & 7) * 258 + (blockIdx.x >> 3);  // XCD swizzle (2064 = 8*258)
  const int kw = bi % 129;
  const int bk = bi / 129;
  const int k = bk & 7, b = bk >> 3;
  const int t = threadIdx.x;
  const int lane = t & 63, wave = t >> 6;
  const int wm = wave >> 2, wn = wave & 3;   // M = 2x96, N = 4x64
  const int lrow = lane & 15;
  const int g = lane >> 4;

  const size_t chstride = 129 * 256;
  const size_t colbase = (((size_t)(b*768 + k*96)) * 129 + kw) * 256;

  // ---- phase A: 12 cols/wave, prefetch 1 batch ahead; chain-twiddle fwd FFT ----
  {
    const float s = 1.f/256.f;
    uint4 cur[4];
#pragma unroll
    for (int cc = 0; cc < 4; ++cc)
      cur[cc] = *reinterpret_cast<const uint4*>(F + colbase + (size_t)(wave*12 + cc)*chstride + 4*lane);
#pragma unroll
    for (int bt = 0; bt < 3; ++bt) {
      uint4 nxt[4];
      if (bt < 2) {
#pragma unroll
        for (int cc = 0; cc < 4; ++cc)
          nxt[cc] = *reinterpret_cast<const uint4*>(F + colbase + (size_t)(wave*12 + (bt+1)*4 + cc)*chstride + 4*lane);
      }
      const int c0 = wave*12 + bt*4;
      float2 v4[4][4];
#pragma unroll
      for (int cc = 0; cc < 4; ++cc) {
        v4[cc][0]=unpack_bf16(cur[cc].x); v4[cc][1]=unpack_bf16(cur[cc].y);
        v4[cc][2]=unpack_bf16(cur[cc].z); v4[cc][3]=unpack_bf16(cur[cc].w);
      }
      float2 tw[4]; int e[4];
#pragma unroll
      for (int r=0;r<4;++r){
        e[r] = (4*lane + r) & 127;
        float sn, cs;
        sincosf(-(float)e[r]*0.0245436926f, &sn, &cs);   // forward si = -1
        tw[r] = make_float2(cs, sn);
      }
      const bool rec = (wave == 0 && bt == 0);
#define A_STAGE(M, SIDX) \
      { if (rec) { _Pragma("unroll") for (int r=0;r<4;++r) Tlds[((SIDX)*4+r)*64 + lane] = tw[r]; } \
        difA_stage<M>(v4, tw, lane); \
        if ((SIDX) < 5) tw_advance(tw, e); }
      A_STAGE(32,0) A_STAGE(16,1) A_STAGE(8,2) A_STAGE(4,3) A_STAGE(2,4) A_STAGE(1,5)
#undef A_STAGE
#pragma unroll
      for (int cc = 0; cc < 4; ++cc) {
        float2* v = v4[cc];
        { float2 a0=v[0], a2=v[2]; v[0]=cadd(a0,a2); v[2]=csub(a0,a2);
          float2 a1=v[1], a3=v[3]; v[1]=cadd(a1,a3); v[3]=cmulj(csub(a1,a3), -1.f); }
        { float2 a=v[0]; v[0]=cadd(a,v[1]); v[1]=csub(a,v[1]);
          float2 c=v[2]; v[2]=cadd(c,v[3]); v[3]=csub(c,v[3]); }
      }
#pragma unroll
      for (int r = 0; r < 4; ++r) {
        int n = 4*lane + r;
        int byte = (n*384 + c0*4) ^ dslot(n);
        uint4 w;
        w.x = pack_bf16(v4[0][r].x*s, v4[0][r].y*s);
        w.y = pack_bf16(v4[1][r].x*s, v4[1][r].y*s);
        w.z = pack_bf16(v4[2][r].x*s, v4[2][r].y*s);
        w.w = pack_bf16(v4[3][r].x*s, v4[3][r].y*s);
        *reinterpret_cast<uint4*>(smem + byte) = w;
      }
      if (bt < 2) {
#pragma unroll
        for (int cc = 0; cc < 4; ++cc) cur[cc] = nxt[cc];
      }
    }
  }
  __syncthreads();

  const bf16x8* W1v = reinterpret_cast<const bf16x8*>(Wt + (size_t)(k*2 + 0) * 18432);
  const bf16x8* W2v = reinterpret_cast<const bf16x8*>(Wt + (size_t)(k*2 + 1) * 18432);

  f32x4 acc[6][4];   // 96 VGPRs

  // ---- layer 1: acc = W1 x D  (bf in PAIRS: live = acc96 + bf8 + af4) ----
#pragma unroll
  for (int mi = 0; mi < 6; ++mi)
#pragma unroll
    for (int ni = 0; ni < 4; ++ni) acc[mi][ni] = (f32x4)0.f;
#pragma unroll
  for (int ks = 0; ks < 6; ++ks) {
#pragma unroll
    for (int nh = 0; nh < 2; ++nh) {
      bf16x8 bfa, bfb;
      {
        int n0 = wn*64 + (2*nh + 0)*16 + lrow;
        int n1 = wn*64 + (2*nh + 1)*16 + lrow;
        bfa = *reinterpret_cast<bf16x8*>(smem + ((n0*384 + ks*64 + g*16) ^ dslot(n0)));
        bfb = *reinterpret_cast<bf16x8*>(smem + ((n1*384 + ks*64 + g*16) ^ dslot(n1)));
      }
#pragma unroll
      for (int mi = 0; mi < 6; ++mi) {
        bf16x8 af = W1v[(wm*96 + mi*16 + lrow)*24 + ks*4 + g];
        acc[mi][2*nh + 0] = __builtin_amdgcn_mfma_f32_16x16x32_bf16(af, bfa, acc[mi][2*nh + 0], 0, 0, 0);
        acc[mi][2*nh + 1] = __builtin_amdgcn_mfma_f32_16x16x32_bf16(af, bfb, acc[mi][2*nh + 1], 0, 0, 0);
      }
    }
  }
  __syncthreads();

  // ---- O1 = relu(acc + b1) -> Dlds in place ----
  {
    const float2* b1k = b1 + k * 96;
#pragma unroll
    for (int mi = 0; mi < 6; ++mi) {
      int m0 = wm*96 + mi*16 + 4*g;
      int o0 = m0 >> 1;
      float2 ba = b1k[o0], bb = b1k[o0 + 1];
#pragma unroll
      for (int ni = 0; ni < 4; ++ni) {
        int n = wn*64 + ni*16 + lrow;
        f32x4 v = acc[mi][ni];
        u32 lo = pack_bf16(fmaxf(v[0] + ba.x, 0.f), fmaxf(v[1] + ba.y, 0.f));
        u32 hi = pack_bf16(fmaxf(v[2] + bb.x, 0.f), fmaxf(v[3] + bb.y, 0.f));
        int byte = (n*384 + m0*2) ^ dslot(n);
        *reinterpret_cast<uint2*>(smem + byte) = make_uint2(lo, hi);
      }
    }
  }
  __syncthreads();

  // ---- layer 2: acc = W2 x O1 ----
#pragma unroll
  for (int mi = 0; mi < 6; ++mi)
#pragma unroll
    for (int ni = 0; ni < 4; ++ni) acc[mi][ni] = (f32x4)0.f;
#pragma unroll
  for (int ks = 0; ks < 6; ++ks) {
#pragma unroll
    for (int nh = 0; nh < 2; ++nh) {
      bf16x8 bfa, bfb;
      {
        int n0 = wn*64 + (2*nh + 0)*16 + lrow;
        int n1 = wn*64 + (2*nh + 1)*16 + lrow;
        bfa = *reinterpret_cast<bf16x8*>(smem + ((n0*384 + ks*64 + g*16) ^ dslot(n0)));
        bfb = *reinterpret_cast<bf16x8*>(smem + ((n1*384 + ks*64 + g*16) ^ dslot(n1)));
      }
#pragma unroll
      for (int mi = 0; mi < 6; ++mi) {
        bf16x8 af = W2v[(wm*96 + mi*16 + lrow)*24 + ks*4 + g];
        acc[mi][2*nh + 0] = __builtin_amdgcn_mfma_f32_16x16x32_bf16(af, bfa, acc[mi][2*nh + 0], 0, 0, 0);
        acc[mi][2*nh + 1] = __builtin_amdgcn_mfma_f32_16x16x32_bf16(af, bfb, acc[mi][2*nh + 1], 0, 0, 0);
      }
    }
  }
  __syncthreads();

  // ---- epilogue: bias2 + softshrink -> Clds [c][n] (dword = c*258 + n) ----
  {
    u32* Clds = reinterpret_cast<u32*>(smem);
    const float2* b2k = b2 + k * 96;
#pragma unroll
    for (int mi = 0; mi < 6; ++mi) {
      int m0 = wm*96 + mi*16 + 4*g;
      int o0 = m0 >> 1;
      float2 ca = b2k[o0], cb = b2k[o0 + 1];
#pragma unroll
      for (int ni = 0; ni < 4; ++ni) {
        int n = wn*64 + ni*16 + lrow;
        f32x4 v = acc[mi][ni];
        Clds[o0*258 + n]       = pack_bf16(sshrink(v[0] + ca.x), sshrink(v[1] + ca.y));
        Clds[(o0 + 1)*258 + n] = pack_bf16(sshrink(v[2] + cb.x), sshrink(v[3] + cb.y));
      }
    }
  }
  __syncthreads();

  // ---- phase C: inverse FFT, twiddles from Tlds (conjugated), uint4 stores ----
  {
    const u32* Clds = reinterpret_cast<const u32*>(smem);
    const float s = 1.f/256.f;
#pragma unroll
    for (int bt = 0; bt < 3; ++bt) {
      const int c0 = wave*12 + bt*4;
      float2 v4[4][4];
#pragma unroll
      for (int cc = 0; cc < 4; ++cc) {
        uint2 q0 = *reinterpret_cast<const uint2*>(Clds + (c0+cc)*258 + 4*lane);
        uint2 q1 = *reinterpret_cast<const uint2*>(Clds + (c0+cc)*258 + 4*lane + 2);
        v4[cc][0]=unpack_bf16(q0.x); v4[cc][1]=unpack_bf16(q0.y);
        v4[cc][2]=unpack_bf16(q1.x); v4[cc][3]=unpack_bf16(q1.y);
      }
#pragma unroll
      for (int cc = 0; cc < 4; ++cc) {
        float2* v = v4[cc];
        { float2 a=v[0]; v[0]=cadd(a,v[1]); v[1]=csub(a,v[1]);
          float2 c=v[2]; v[2]=cadd(c,v[3]); v[3]=csub(c,v[3]); }
        { v[3] = cmulj(v[3], 1.f);
          float2 a0=v[0]; v[0]=cadd(a0,v[2]); v[2]=csub(a0,v[2]);
          float2 a1=v[1]; v[1]=cadd(a1,v[3]); v[3]=csub(a1,v[3]); }
      }
      float2 tw[4];
#define C_STAGE(M, SIDX) \
      { _Pragma("unroll") for (int r=0;r<4;++r) tw[r] = Tlds[((SIDX)*4+r)*64 + lane]; \
        ditC_stage<M>(v4, tw, lane); }
      C_STAGE(1,5) C_STAGE(2,4) C_STAGE(4,3) C_STAGE(8,2) C_STAGE(16,1) C_STAGE(32,0)
#undef C_STAGE
#pragma unroll
      for (int cc = 0; cc < 4; ++cc) {
        uint4 o;
        o.x = pack_bf16(v4[cc][0].x*s, v4[cc][0].y*s);
        o.y = pack_bf16(v4[cc][1].x*s, v4[cc][1].y*s);
        o.z = pack_bf16(v4[cc][2].x*s, v4[cc][2].y*s);
        o.w = pack_bf16(v4[cc][3].x*s, v4[cc][3].y*s);
        *reinterpret_cast<uint4*>(F + colbase + (size_t)(c0+cc)*chstride + 4*lane) = o;
      }
    }
  }
}

// ---------------- Pass 5: row irfft (Hermitian ext), 2 rows per FFT, + bias ------
__global__ __launch_bounds__(256) void k_rowifft(const u32* __restrict__ F,
                                                 const float* __restrict__ x,
                                                 float* __restrict__ out) {
  __shared__ u32 stage[131*65];
  const int bc = blockIdx.x >> 2, hc = blockIdx.x & 3;
  const int tid = threadIdx.x, wave = tid >> 6, lane = tid & 63;
  Tw T = make_tw(lane, 1.f);
  for (int idx = tid; idx < 129*64; idx += 256) {
    int kw = idx >> 6, hl = idx & 63;
    stage[stage_row(kw)*65 + hl] = F[((size_t)bc*129 + kw)*256 + hc*64 + hl];
  }
  __syncthreads();

  const int L = brev6(lane);
#pragma unroll
  for (int rr = 0; rr < 8; ++rr) {
    const int hl0 = wave*16 + rr*2, hl1 = hl0 + 1;
    const float* xa = x + ((size_t)bc*256 + hc*64 + hl0) * 256;
    float xv0[4], xv1[4];
#pragma unroll
    for (int r=0;r<4;++r){ xv0[r]=xa[lane+64*r]; xv1[r]=xa[256+lane+64*r]; }
    float2 v[4];
#pragma unroll
    for (int r=0;r<4;++r) {
      int c = ((r&1)<<1) | (r>>1);
      int kw = 4*L + c;
      int src = (kw <= 128) ? kw : 256 - kw;
      float sg = (kw <= 128) ? 1.f : -1.f;
      int row = stage_row(src);
      float2 a = unpack_bf16(stage[row*65 + hl0]);
      float2 b = unpack_bf16(stage[row*65 + hl1]);
      a.y *= sg; b.y *= sg;
      if (kw == 0 || kw == 128) { a.y = 0.f; b.y = 0.f; }
      v[r] = make_float2(a.x - b.y, a.y + b.x);
    }
    fft256_dit(v, lane, T);
    float* oa = out + ((size_t)bc*256 + hc*64 + hl0) * 256;
#pragma unroll
    for (int r=0;r<4;++r) {
      int d = lane + 64*r;
      oa[d]       = v[r].x + xv0[r];
      oa[256 + d] = v[r].y + xv1[r];
    }
  }
}

extern "C" void kernel_launch(void* const* d_in, const int* in_sizes, int n_in,
                              void* d_out, int out_size, void* d_ws, size_t ws_size,
                              hipStream_t stream) {
  const float* x   = (const float*)d_in[0];
  const float2* w1 = (const float2*)d_in[1];
  const float2* b1 = (const float2*)d_in[2];
  const float2* w2 = (const float2*)d_in[3];
  const float2* b2 = (const float2*)d_in[4];
  float* out = (float*)d_out;
  u32* F = (u32*)d_ws;            // 1536*129*256*4 B ~ 203 MB
  u32* Wt = (u32*)d_out;          // d_out head as scratch; overwritten by k_rowifft

  (void)hipFuncSetAttribute(reinterpret_cast<const void*>(k_colmix),
                            hipFuncAttributeMaxDynamicSharedMemorySize, CM_LDS_BYTES);

  const int n_rows_blocks = 1536 * 4;
  const int n_cm_blocks   = 2 * 8 * 129;   // 2064 = 8 * 258

  k_prep_w<<<16, 256, 0, stream>>>(w1, w2, Wt);
  k_rowfft<<<n_rows_blocks, 256, 0, stream>>>(x, F);
  k_colmix<<<n_cm_blocks, 512, CM_LDS_BYTES, stream>>>(F, Wt, b1, b2);
  k_rowifft<<<n_rows_blocks, 256, 0, stream>>>(F, x, out);
}

// Round 15
// 816.193 us; speedup vs baseline: 1.0259x; 1.0259x over previous
//
#include <hip/hip_runtime.h>
#include <hip/hip_bf16.h>
#include <math.h>

// DistributedAFNO2D: out = x + irfft2( blockMLP( rfft2(x, ortho) ), ortho )
// B=2, C=768, H=W=256, 8 blocks x 96 ch, KW = 129 frequency cols.
// F in d_ws: bf16-packed complex (u32 = [imag:bf16 | real:bf16]), layout (B*C, KW, H).
// Passes: rowfft -> [fused: colFFT + MFMA mix + inv colFFT] -> rowifft.
// colmix: 512 thr / 128 VGPRs; chain twiddles (A) + LDS twiddle table (C);
// DPP/swizzle lane exchanges; phase-A prefetch; GEMM: bf[4] per ks + af
// 2-deep double-buffer (round 15: stops compiler hoisting 6 af loads, which
// pushed live regs to ~136 and spilled ~80MB).

#define LAMBDA_SS 0.01f

typedef unsigned int u32;
typedef __attribute__((ext_vector_type(8))) short bf16x8;
typedef __attribute__((ext_vector_type(4))) float f32x4;

__device__ __forceinline__ u32 pack_bf16(float r, float i) {
  union { float f; u32 u; } ur, ui;
  ur.f = r; ui.f = i;
  u32 rb = (ur.u + 0x7FFFu + ((ur.u >> 16) & 1u)) >> 16;
  u32 ib = (ui.u + 0x7FFFu + ((ui.u >> 16) & 1u)) >> 16;
  return (ib << 16) | (rb & 0xFFFFu);
}

__device__ __forceinline__ float2 unpack_bf16(u32 p) {
  union { u32 u; float f; } a, b;
  a.u = (p & 0xFFFFu) << 16;
  b.u = (p & 0xFFFF0000u);
  return make_float2(a.f, b.f);
}

__device__ __forceinline__ float sshrink(float v) {
  return (v > LAMBDA_SS) ? v - LAMBDA_SS : ((v < -LAMBDA_SS) ? v + LAMBDA_SS : 0.f);
}

// ---------------- register FFT machinery (shared helpers) ----------------
__device__ __forceinline__ float2 cadd(float2 a, float2 b){ return make_float2(a.x+b.x, a.y+b.y); }
__device__ __forceinline__ float2 csub(float2 a, float2 b){ return make_float2(a.x-b.x, a.y-b.y); }
__device__ __forceinline__ float2 cmul(float2 a, float2 b){
  return make_float2(fmaf(a.x,b.x,-a.y*b.y), fmaf(a.x,b.y,a.y*b.x));
}
__device__ __forceinline__ float2 cmulj(float2 a, float si){  // a * (si*i)
  return make_float2(-si*a.y, si*a.x);
}
__device__ __forceinline__ float2 shflx(float2 v, int m){
  return make_float2(__shfl_xor(v.x, m, 64), __shfl_xor(v.y, m, 64));
}
__device__ __forceinline__ float2 shfll(float2 v, int l){
  return make_float2(__shfl(v.x, l, 64), __shfl(v.y, l, 64));
}
__device__ __forceinline__ int brev6(int x){ return (int)(__brev((u32)x) >> 26); }

// lane exchange by XOR mask M: DPP for 1/2, ds_swizzle for 4/8/16, shfl for 32
template<int M>
__device__ __forceinline__ float xl(float x){
  if constexpr (M == 32) {
    return __shfl_xor(x, 32, 64);
  } else if constexpr (M >= 4) {
    return __int_as_float(__builtin_amdgcn_ds_swizzle(__float_as_int(x), (M << 10) | 0x1F));
  } else {
    constexpr int ctrl = (M == 2) ? 0x4E : 0xB1;   // quad_perm [2,3,0,1] / [1,0,3,2]
    return __int_as_float(__builtin_amdgcn_update_dpp(0, __float_as_int(x), ctrl, 0xF, 0xF, true));
  }
}
template<int M>
__device__ __forceinline__ float2 xch2(float2 v){ return make_float2(xl<M>(v.x), xl<M>(v.y)); }

// ======== layout A: d = lane + 64r (row kernels) ========
struct Tw { float2 t128, t64, t32, t16, t8, t4; float si; };

__device__ __forceinline__ float2 mkTw(int e, float si){
  float a = (float)e * 0.0245436926f;   // 2*pi/256
  return make_float2(cosf(a), si*sinf(a));
}
__device__ __forceinline__ Tw make_tw(int lane, float si){
  Tw w; w.si = si;
  w.t128 = mkTw(lane, si);
  w.t64  = mkTw(2*lane, si);
  w.t32  = mkTw((lane&31)*4, si);
  w.t16  = mkTw((lane&15)*8, si);
  w.t8   = mkTw((lane&7)*16, si);
  w.t4   = mkTw((lane&3)*32, si);
  return w;
}

__device__ __forceinline__ float2 bfly_dif(float2 v, int h, float2 th, int lane){
  float2 p = shflx(v, h);
  float sx = (lane & h) ? -1.f : 1.f;
  float2 s = make_float2(fmaf(sx, v.x, p.x), fmaf(sx, v.y, p.y));
  if (lane & h) s = cmul(s, th);
  return s;
}
__device__ __forceinline__ float2 bfly_dit(float2 v, int h, float2 th, int lane){
  if (lane & h) v = cmul(v, th);
  float2 p = shflx(v, h);
  float sx = (lane & h) ? -1.f : 1.f;
  return make_float2(fmaf(sx, v.x, p.x), fmaf(sx, v.y, p.y));
}

__device__ __forceinline__ void fft256_dif(float2 v[4], int lane, const Tw& T){
  float2 t128b = cmulj(T.t128, T.si);
  { float2 a=v[0], b=v[2]; v[0]=cadd(a,b); v[2]=cmul(csub(a,b), T.t128);
    float2 c=v[1], d=v[3]; v[1]=cadd(c,d); v[3]=cmul(csub(c,d), t128b); }
  { float2 a=v[0], b=v[1]; v[0]=cadd(a,b); v[1]=cmul(csub(a,b), T.t64);
    float2 c=v[2], d=v[3]; v[2]=cadd(c,d); v[3]=cmul(csub(c,d), T.t64); }
#pragma unroll
  for (int r=0;r<4;++r) v[r]=bfly_dif(v[r],32,T.t32,lane);
#pragma unroll
  for (int r=0;r<4;++r) v[r]=bfly_dif(v[r],16,T.t16,lane);
#pragma unroll
  for (int r=0;r<4;++r) v[r]=bfly_dif(v[r],8,T.t8,lane);
#pragma unroll
  for (int r=0;r<4;++r) v[r]=bfly_dif(v[r],4,T.t4,lane);
#pragma unroll
  for (int r=0;r<4;++r){
    float2 p=shflx(v[r],2);
    float sx=(lane&2)?-1.f:1.f;
    float2 s=make_float2(fmaf(sx,v[r].x,p.x), fmaf(sx,v[r].y,p.y));
    if ((lane&3)==3) s=cmulj(s,T.si);
    v[r]=s;
  }
#pragma unroll
  for (int r=0;r<4;++r){
    float2 p=shflx(v[r],1);
    float sx=(lane&1)?-1.f:1.f;
    v[r]=make_float2(fmaf(sx,v[r].x,p.x), fmaf(sx,v[r].y,p.y));
  }
}

__device__ __forceinline__ void fft256_dit(float2 v[4], int lane, const Tw& T){
#pragma unroll
  for (int r=0;r<4;++r){
    float2 p=shflx(v[r],1);
    float sx=(lane&1)?-1.f:1.f;
    v[r]=make_float2(fmaf(sx,v[r].x,p.x), fmaf(sx,v[r].y,p.y));
  }
#pragma unroll
  for (int r=0;r<4;++r){
    float2 w=v[r];
    if ((lane&3)==3) w=cmulj(w,T.si);
    float2 p=shflx(w,2);
    float sx=(lane&2)?-1.f:1.f;
    v[r]=make_float2(fmaf(sx,w.x,p.x), fmaf(sx,w.y,p.y));
  }
#pragma unroll
  for (int r=0;r<4;++r) v[r]=bfly_dit(v[r],4,T.t4,lane);
#pragma unroll
  for (int r=0;r<4;++r) v[r]=bfly_dit(v[r],8,T.t8,lane);
#pragma unroll
  for (int r=0;r<4;++r) v[r]=bfly_dit(v[r],16,T.t16,lane);
#pragma unroll
  for (int r=0;r<4;++r) v[r]=bfly_dit(v[r],32,T.t32,lane);
  { v[1]=cmul(v[1],T.t64); float2 a=v[0]; v[0]=cadd(a,v[1]); v[1]=csub(a,v[1]);
    v[3]=cmul(v[3],T.t64); float2 c=v[2]; v[2]=cadd(c,v[3]); v[3]=csub(c,v[3]); }
  { v[2]=cmul(v[2],T.t128); v[3]=cmul(v[3], cmulj(T.t128,T.si));
    float2 a=v[0]; v[0]=cadd(a,v[2]); v[2]=csub(a,v[2]);
    float2 b=v[1]; v[1]=cadd(b,v[3]); v[3]=csub(b,v[3]); }
}

// ======== layout B: d = 4*lane + r (colmix; chain twiddles + LDS table) ========
template<int M>
__device__ __forceinline__ void difA_stage(float2 v4[4][4], const float2 tw[4], int lane){
#pragma unroll
  for (int r=0;r<4;++r){
#pragma unroll
    for (int cc=0;cc<4;++cc){
      float2 p = xch2<M>(v4[cc][r]);
      float sx = (lane & M) ? -1.f : 1.f;
      float2 t = make_float2(fmaf(sx, v4[cc][r].x, p.x), fmaf(sx, v4[cc][r].y, p.y));
      float2 tm = cmul(t, tw[r]);
      v4[cc][r] = (lane & M) ? tm : t;
    }
  }
}
template<int M>
__device__ __forceinline__ void ditC_stage(float2 v4[4][4], const float2 tw[4], int lane){
#pragma unroll
  for (int r=0;r<4;++r){
#pragma unroll
    for (int cc=0;cc<4;++cc){
      float2 w = v4[cc][r];
      float2 wm_ = make_float2(fmaf(w.x, tw[r].x,  w.y*tw[r].y),
                               fmaf(w.y, tw[r].x, -w.x*tw[r].y));
      float2 u = (lane & M) ? wm_ : w;
      float2 p = xch2<M>(u);
      float sx = (lane & M) ? -1.f : 1.f;
      v4[cc][r] = make_float2(fmaf(sx, u.x, p.x), fmaf(sx, u.y, p.y));
    }
  }
}
__device__ __forceinline__ void tw_advance(float2 tw[4], int e[4]){
#pragma unroll
  for (int r=0;r<4;++r){
    float2 sq = cmul(tw[r], tw[r]);
    if (e[r] & 64) { sq.x = -sq.x; sq.y = -sq.y; }
    e[r] = (2*e[r]) & 127;
    tw[r] = sq;
  }
}

__device__ __forceinline__ int stage_row(int kw){ return 33*(kw&3) + (kw>>2); }
__device__ __forceinline__ int dslot(int n){ return (((n>>2)&7) ^ ((n&3)<<1)) << 4; }

// ---------------- Pass 1: row rfft, 2 real rows per complex FFT ----------------
__global__ __launch_bounds__(256) void k_rowfft(const float* __restrict__ x, u32* __restrict__ F) {
  __shared__ u32 stage[131*65];
  const int bc = blockIdx.x >> 2, hc = blockIdx.x & 3;
  const int tid = threadIdx.x, wave = tid >> 6, lane = tid & 63;
  Tw T = make_tw(lane, -1.f);
  const int L = brev6(lane);
  const int laneP0 = brev6((64 - L) & 63);
  const int lanePX = 63 - lane;

  float cx0[4], cx1[4];
  {
    const float* xa = x + ((size_t)bc*256 + hc*64 + wave*16) * 256;
#pragma unroll
    for (int r=0;r<4;++r){ cx0[r]=xa[lane+64*r]; cx1[r]=xa[256+lane+64*r]; }
  }
#pragma unroll
  for (int rr = 0; rr < 8; ++rr) {
    const int hl0 = wave*16 + rr*2, hl1 = hl0 + 1;
    float nx0[4], nx1[4];
    if (rr < 7) {
      const float* xb = x + ((size_t)bc*256 + hc*64 + hl0 + 2) * 256;
#pragma unroll
      for (int r=0;r<4;++r){ nx0[r]=xb[lane+64*r]; nx1[r]=xb[256+lane+64*r]; }
    }
    float2 v[4];
#pragma unroll
    for (int r=0;r<4;++r) v[r] = make_float2(cx0[r], cx1[r]);
    fft256_dif(v, lane, T);
#define UNSCR(R, RP, C, LP) { \
      float2 z = v[R]; float2 p = shfll(v[RP], LP); \
      float2 A  = make_float2(0.5f*(z.x+p.x), 0.5f*(z.y-p.y)); \
      float2 Bv = make_float2(0.5f*(z.y+p.y), 0.5f*(p.x-z.x)); \
      int kw = 4*L + (C); \
      if (kw <= 128) { int row = stage_row(kw); \
        stage[row*65 + hl0] = pack_bf16(A.x, A.y); \
        stage[row*65 + hl1] = pack_bf16(Bv.x, Bv.y); } }
    UNSCR(0, 0, 0, laneP0)
    UNSCR(1, 1, 2, lanePX)
    UNSCR(2, 3, 1, lanePX)
    UNSCR(3, 2, 3, lanePX)
#undef UNSCR
    if (rr < 7) {
#pragma unroll
      for (int r=0;r<4;++r){ cx0[r]=nx0[r]; cx1[r]=nx1[r]; }
    }
  }
  __syncthreads();
  for (int idx = tid; idx < 129*64; idx += 256) {
    int kw = idx >> 6, hl = idx & 63;
    F[((size_t)bc*129 + kw)*256 + hc*64 + hl] = stage[stage_row(kw)*65 + hl];
  }
}

// ---------------- Weight prep ----------------
__global__ __launch_bounds__(256) void k_prep_w(const float2* __restrict__ w1,
                                                const float2* __restrict__ w2,
                                                u32* __restrict__ Wt) {
  const int blk = blockIdx.x;      // k*2 + layer
  const int k = blk >> 1, layer = blk & 1;
  const float2* w = (layer == 0 ? w1 : w2) + (size_t)k * 96 * 96;
  u32* out = Wt + (size_t)blk * 18432;
  for (int idx = threadIdx.x; idx < 9216; idx += 256) {
    int o = idx % 96, i = idx / 96;
    float2 v = w[i * 96 + o];
    out[(2 * o) * 96 + i]     = pack_bf16(v.x, -v.y);
    out[(2 * o + 1) * 96 + i] = pack_bf16(v.y, v.x);
  }
}

// ---------------- Fused pass: colFFT + MFMA mix + inv colFFT, per (b,k,kw) -------
// 512 thr / 8 waves (2 wm x 4 wn). LDS (111360 B):
//   [0, 98304):      Dlds[n=0..255][kk=0..191] bf16, byte = n*384 + kk*2 ^ dslot(n)
//   [0, 99072):      Clds[c=0..95][n] u32 (phase C staging; overlaps Dlds)
//   [99072, 111360): Tlds[24][64] float2 forward twiddles (s*4+r major, lane minor)
#define CM_LDS_BYTES 111360
#define TLDS_OFF     99072

__global__ __launch_bounds__(512, 2) void k_colmix(u32* __restrict__ F,
    const u32* __restrict__ Wt,
    const float2* __restrict__ b1, const float2* __restrict__ b2) {
  extern __shared__ char smem[];
  float2* Tlds = reinterpret_cast<float2*>(smem + TLDS_OFF);

  const int bi = (blockIdx.x & 7) * 258 + (blockIdx.x >> 3);  // XCD swizzle (2064 = 8*258)
  const int kw = bi % 129;
  const int bk = bi / 129;
  const int k = bk & 7, b = bk >> 3;
  const int t = threadIdx.x;
  const int lane = t & 63, wave = t >> 6;
  const int wm = wave >> 2, wn = wave & 3;   // M = 2x96, N = 4x64
  const int lrow = lane & 15;
  const int g = lane >> 4;

  const size_t chstride = 129 * 256;
  const size_t colbase = (((size_t)(b*768 + k*96)) * 129 + kw) * 256;

  // ---- phase A: 12 cols/wave, prefetch 1 batch ahead; chain-twiddle fwd FFT ----
  {
    const float s = 1.f/256.f;
    uint4 cur[4];
#pragma unroll
    for (int cc = 0; cc < 4; ++cc)
      cur[cc] = *reinterpret_cast<const uint4*>(F + colbase + (size_t)(wave*12 + cc)*chstride + 4*lane);
#pragma unroll
    for (int bt = 0; bt < 3; ++bt) {
      uint4 nxt[4];
      if (bt < 2) {
#pragma unroll
        for (int cc = 0; cc < 4; ++cc)
          nxt[cc] = *reinterpret_cast<const uint4*>(F + colbase + (size_t)(wave*12 + (bt+1)*4 + cc)*chstride + 4*lane);
      }
      const int c0 = wave*12 + bt*4;
      float2 v4[4][4];
#pragma unroll
      for (int cc = 0; cc < 4; ++cc) {
        v4[cc][0]=unpack_bf16(cur[cc].x); v4[cc][1]=unpack_bf16(cur[cc].y);
        v4[cc][2]=unpack_bf16(cur[cc].z); v4[cc][3]=unpack_bf16(cur[cc].w);
      }
      float2 tw[4]; int e[4];
#pragma unroll
      for (int r=0;r<4;++r){
        e[r] = (4*lane + r) & 127;
        float sn, cs;
        sincosf(-(float)e[r]*0.0245436926f, &sn, &cs);   // forward si = -1
        tw[r] = make_float2(cs, sn);
      }
      const bool rec = (wave == 0 && bt == 0);
#define A_STAGE(M, SIDX) \
      { if (rec) { _Pragma("unroll") for (int r=0;r<4;++r) Tlds[((SIDX)*4+r)*64 + lane] = tw[r]; } \
        difA_stage<M>(v4, tw, lane); \
        if ((SIDX) < 5) tw_advance(tw, e); }
      A_STAGE(32,0) A_STAGE(16,1) A_STAGE(8,2) A_STAGE(4,3) A_STAGE(2,4) A_STAGE(1,5)
#undef A_STAGE
#pragma unroll
      for (int cc = 0; cc < 4; ++cc) {
        float2* v = v4[cc];
        { float2 a0=v[0], a2=v[2]; v[0]=cadd(a0,a2); v[2]=csub(a0,a2);
          float2 a1=v[1], a3=v[3]; v[1]=cadd(a1,a3); v[3]=cmulj(csub(a1,a3), -1.f); }
        { float2 a=v[0]; v[0]=cadd(a,v[1]); v[1]=csub(a,v[1]);
          float2 c=v[2]; v[2]=cadd(c,v[3]); v[3]=csub(c,v[3]); }
      }
#pragma unroll
      for (int r = 0; r < 4; ++r) {
        int n = 4*lane + r;
        int byte = (n*384 + c0*4) ^ dslot(n);
        uint4 w;
        w.x = pack_bf16(v4[0][r].x*s, v4[0][r].y*s);
        w.y = pack_bf16(v4[1][r].x*s, v4[1][r].y*s);
        w.z = pack_bf16(v4[2][r].x*s, v4[2][r].y*s);
        w.w = pack_bf16(v4[3][r].x*s, v4[3][r].y*s);
        *reinterpret_cast<uint4*>(smem + byte) = w;
      }
      if (bt < 2) {
#pragma unroll
        for (int cc = 0; cc < 4; ++cc) cur[cc] = nxt[cc];
      }
    }
  }
  __syncthreads();

  const bf16x8* W1v = reinterpret_cast<const bf16x8*>(Wt + (size_t)(k*2 + 0) * 18432);
  const bf16x8* W2v = reinterpret_cast<const bf16x8*>(Wt + (size_t)(k*2 + 1) * 18432);

  f32x4 acc[6][4];   // 96 VGPRs

  // ---- layer 1: acc = W1 x D  (bf[4] per ks; af 2-deep pipeline) ----
#pragma unroll
  for (int mi = 0; mi < 6; ++mi)
#pragma unroll
    for (int ni = 0; ni < 4; ++ni) acc[mi][ni] = (f32x4)0.f;
#pragma unroll
  for (int ks = 0; ks < 6; ++ks) {
    bf16x8 bf[4];
#pragma unroll
    for (int ni = 0; ni < 4; ++ni) {
      int n = wn*64 + ni*16 + lrow;
      bf[ni] = *reinterpret_cast<bf16x8*>(smem + ((n*384 + ks*64 + g*16) ^ dslot(n)));
    }
    bf16x8 af0 = W1v[(wm*96 + 0*16 + lrow)*24 + ks*4 + g];
#pragma unroll
    for (int mi = 0; mi < 6; ++mi) {
      bf16x8 afn;
      if (mi < 5) afn = W1v[(wm*96 + (mi+1)*16 + lrow)*24 + ks*4 + g];
#pragma unroll
      for (int ni = 0; ni < 4; ++ni)
        acc[mi][ni] = __builtin_amdgcn_mfma_f32_16x16x32_bf16(af0, bf[ni], acc[mi][ni], 0, 0, 0);
      af0 = afn;
    }
  }
  __syncthreads();

  // ---- O1 = relu(acc + b1) -> Dlds in place ----
  {
    const float2* b1k = b1 + k * 96;
#pragma unroll
    for (int mi = 0; mi < 6; ++mi) {
      int m0 = wm*96 + mi*16 + 4*g;
      int o0 = m0 >> 1;
      float2 ba = b1k[o0], bb = b1k[o0 + 1];
#pragma unroll
      for (int ni = 0; ni < 4; ++ni) {
        int n = wn*64 + ni*16 + lrow;
        f32x4 v = acc[mi][ni];
        u32 lo = pack_bf16(fmaxf(v[0] + ba.x, 0.f), fmaxf(v[1] + ba.y, 0.f));
        u32 hi = pack_bf16(fmaxf(v[2] + bb.x, 0.f), fmaxf(v[3] + bb.y, 0.f));
        int byte = (n*384 + m0*2) ^ dslot(n);
        *reinterpret_cast<uint2*>(smem + byte) = make_uint2(lo, hi);
      }
    }
  }
  __syncthreads();

  // ---- layer 2: acc = W2 x O1 ----
#pragma unroll
  for (int mi = 0; mi < 6; ++mi)
#pragma unroll
    for (int ni = 0; ni < 4; ++ni) acc[mi][ni] = (f32x4)0.f;
#pragma unroll
  for (int ks = 0; ks < 6; ++ks) {
    bf16x8 bf[4];
#pragma unroll
    for (int ni = 0; ni < 4; ++ni) {
      int n = wn*64 + ni*16 + lrow;
      bf[ni] = *reinterpret_cast<bf16x8*>(smem + ((n*384 + ks*64 + g*16) ^ dslot(n)));
    }
    bf16x8 af0 = W2v[(wm*96 + 0*16 + lrow)*24 + ks*4 + g];
#pragma unroll
    for (int mi = 0; mi < 6; ++mi) {
      bf16x8 afn;
      if (mi < 5) afn = W2v[(wm*96 + (mi+1)*16 + lrow)*24 + ks*4 + g];
#pragma unroll
      for (int ni = 0; ni < 4; ++ni)
        acc[mi][ni] = __builtin_amdgcn_mfma_f32_16x16x32_bf16(af0, bf[ni], acc[mi][ni], 0, 0, 0);
      af0 = afn;
    }
  }
  __syncthreads();

  // ---- epilogue: bias2 + softshrink -> Clds [c][n] (dword = c*258 + n) ----
  {
    u32* Clds = reinterpret_cast<u32*>(smem);
    const float2* b2k = b2 + k * 96;
#pragma unroll
    for (int mi = 0; mi < 6; ++mi) {
      int m0 = wm*96 + mi*16 + 4*g;
      int o0 = m0 >> 1;
      float2 ca = b2k[o0], cb = b2k[o0 + 1];
#pragma unroll
      for (int ni = 0; ni < 4; ++ni) {
        int n = wn*64 + ni*16 + lrow;
        f32x4 v = acc[mi][ni];
        Clds[o0*258 + n]       = pack_bf16(sshrink(v[0] + ca.x), sshrink(v[1] + ca.y));
        Clds[(o0 + 1)*258 + n] = pack_bf16(sshrink(v[2] + cb.x), sshrink(v[3] + cb.y));
      }
    }
  }
  __syncthreads();

  // ---- phase C: inverse FFT, twiddles from Tlds (conjugated), uint4 stores ----
  {
    const u32* Clds = reinterpret_cast<const u32*>(smem);
    const float s = 1.f/256.f;
#pragma unroll
    for (int bt = 0; bt < 3; ++bt) {
      const int c0 = wave*12 + bt*4;
      float2 v4[4][4];
#pragma unroll
      for (int cc = 0; cc < 4; ++cc) {
        uint2 q0 = *reinterpret_cast<const uint2*>(Clds + (c0+cc)*258 + 4*lane);
        uint2 q1 = *reinterpret_cast<const uint2*>(Clds + (c0+cc)*258 + 4*lane + 2);
        v4[cc][0]=unpack_bf16(q0.x); v4[cc][1]=unpack_bf16(q0.y);
        v4[cc][2]=unpack_bf16(q1.x); v4[cc][3]=unpack_bf16(q1.y);
      }
#pragma unroll
      for (int cc = 0; cc < 4; ++cc) {
        float2* v = v4[cc];
        { float2 a=v[0]; v[0]=cadd(a,v[1]); v[1]=csub(a,v[1]);
          float2 c=v[2]; v[2]=cadd(c,v[3]); v[3]=csub(c,v[3]); }
        { v[3] = cmulj(v[3], 1.f);
          float2 a0=v[0]; v[0]=cadd(a0,v[2]); v[2]=csub(a0,v[2]);
          float2 a1=v[1]; v[1]=cadd(a1,v[3]); v[3]=csub(a1,v[3]); }
      }
      float2 tw[4];
#define C_STAGE(M, SIDX) \
      { _Pragma("unroll") for (int r=0;r<4;++r) tw[r] = Tlds[((SIDX)*4+r)*64 + lane]; \
        ditC_stage<M>(v4, tw, lane); }
      C_STAGE(1,5) C_STAGE(2,4) C_STAGE(4,3) C_STAGE(8,2) C_STAGE(16,1) C_STAGE(32,0)
#undef C_STAGE
#pragma unroll
      for (int cc = 0; cc < 4; ++cc) {
        uint4 o;
        o.x = pack_bf16(v4[cc][0].x*s, v4[cc][0].y*s);
        o.y = pack_bf16(v4[cc][1].x*s, v4[cc][1].y*s);
        o.z = pack_bf16(v4[cc][2].x*s, v4[cc][2].y*s);
        o.w = pack_bf16(v4[cc][3].x*s, v4[cc][3].y*s);
        *reinterpret_cast<uint4*>(F + colbase + (size_t)(c0+cc)*chstride + 4*lane) = o;
      }
    }
  }
}

// ---------------- Pass 5: row irfft (Hermitian ext), 2 rows per FFT, + bias ------
__global__ __launch_bounds__(256) void k_rowifft(const u32* __restrict__ F,
                                                 const float* __restrict__ x,
                                                 float* __restrict__ out) {
  __shared__ u32 stage[131*65];
  const int bc = blockIdx.x >> 2, hc = blockIdx.x & 3;
  const int tid = threadIdx.x, wave = tid >> 6, lane = tid & 63;
  Tw T = make_tw(lane, 1.f);
  for (int idx = tid; idx < 129*64; idx += 256) {
    int kw = idx >> 6, hl = idx & 63;
    stage[stage_row(kw)*65 + hl] = F[((size_t)bc*129 + kw)*256 + hc*64 + hl];
  }
  __syncthreads();

  const int L = brev6(lane);
#pragma unroll
  for (int rr = 0; rr < 8; ++rr) {
    const int hl0 = wave*16 + rr*2, hl1 = hl0 + 1;
    const float* xa = x + ((size_t)bc*256 + hc*64 + hl0) * 256;
    float xv0[4], xv1[4];
#pragma unroll
    for (int r=0;r<4;++r){ xv0[r]=xa[lane+64*r]; xv1[r]=xa[256+lane+64*r]; }
    float2 v[4];
#pragma unroll
    for (int r=0;r<4;++r) {
      int c = ((r&1)<<1) | (r>>1);
      int kw = 4*L + c;
      int src = (kw <= 128) ? kw : 256 - kw;
      float sg = (kw <= 128) ? 1.f : -1.f;
      int row = stage_row(src);
      float2 a = unpack_bf16(stage[row*65 + hl0]);
      float2 b = unpack_bf16(stage[row*65 + hl1]);
      a.y *= sg; b.y *= sg;
      if (kw == 0 || kw == 128) { a.y = 0.f; b.y = 0.f; }
      v[r] = make_float2(a.x - b.y, a.y + b.x);
    }
    fft256_dit(v, lane, T);
    float* oa = out + ((size_t)bc*256 + hc*64 + hl0) * 256;
#pragma unroll
    for (int r=0;r<4;++r) {
      int d = lane + 64*r;
      oa[d]       = v[r].x + xv0[r];
      oa[256 + d] = v[r].y + xv1[r];
    }
  }
}

extern "C" void kernel_launch(void* const* d_in, const int* in_sizes, int n_in,
                              void* d_out, int out_size, void* d_ws, size_t ws_size,
                              hipStream_t stream) {
  const float* x   = (const float*)d_in[0];
  const float2* w1 = (const float2*)d_in[1];
  const float2* b1 = (const float2*)d_in[2];
  const float2* w2 = (const float2*)d_in[3];
  const float2* b2 = (const float2*)d_in[4];
  float* out = (float*)d_out;
  u32* F = (u32*)d_ws;            // 1536*129*256*4 B ~ 203 MB
  u32* Wt = (u32*)d_out;          // d_out head as scratch; overwritten by k_rowifft

  (void)hipFuncSetAttribute(reinterpret_cast<const void*>(k_colmix),
                            hipFuncAttributeMaxDynamicSharedMemorySize, CM_LDS_BYTES);

  const int n_rows_blocks = 1536 * 4;
  const int n_cm_blocks   = 2 * 8 * 129;   // 2064 = 8 * 258

  k_prep_w<<<16, 256, 0, stream>>>(w1, w2, Wt);
  k_rowfft<<<n_rows_blocks, 256, 0, stream>>>(x, F);
  k_colmix<<<n_cm_blocks, 512, CM_LDS_BYTES, stream>>>(F, Wt, b1, b2);
  k_rowifft<<<n_rows_blocks, 256, 0, stream>>>(F, x, out);
}

// Round 16
// 785.827 us; speedup vs baseline: 1.0656x; 1.0386x over previous
//
#include <hip/hip_runtime.h>
#include <hip/hip_bf16.h>
#include <math.h>

// DistributedAFNO2D: out = x + irfft2( blockMLP( rfft2(x, ortho) ), ortho )
// B=2, C=768, H=W=256, 8 blocks x 96 ch, KW = 129 frequency cols.
// F in d_ws: bf16-packed complex (u32 = [imag:bf16 | real:bf16]), layout (B*C, KW, H).
// Passes: rowfft -> [fused: colFFT + MFMA mix + inv colFFT] -> rowifft.
// colmix: 512 thr / 128 VGPRs; chain twiddles batch-0 + LDS table readback for
// all later batches and phase C; DPP/swizzle lane exchanges; phase-A prefetch;
// GEMM bf[4]/ks + af 2-deep pipeline. Round 16: pack via v_cvt_pk_bf16_f32
// (__float22bfloat162_rn) - 1 VALU op instead of ~8 per complex store.

#define LAMBDA_SS 0.01f

typedef unsigned int u32;
typedef __attribute__((ext_vector_type(8))) short bf16x8;
typedef __attribute__((ext_vector_type(4))) float f32x4;

__device__ __forceinline__ u32 pack_bf16(float r, float i) {
  union { __hip_bfloat162 h; u32 u; } cv;
  cv.h = __float22bfloat162_rn(make_float2(r, i));   // backend: v_cvt_pk_bf16_f32
  return cv.u;
}

__device__ __forceinline__ float2 unpack_bf16(u32 p) {
  union { u32 u; float f; } a, b;
  a.u = (p & 0xFFFFu) << 16;
  b.u = (p & 0xFFFF0000u);
  return make_float2(a.f, b.f);
}

__device__ __forceinline__ float sshrink(float v) {
  return (v > LAMBDA_SS) ? v - LAMBDA_SS : ((v < -LAMBDA_SS) ? v + LAMBDA_SS : 0.f);
}

// ---------------- register FFT machinery (shared helpers) ----------------
__device__ __forceinline__ float2 cadd(float2 a, float2 b){ return make_float2(a.x+b.x, a.y+b.y); }
__device__ __forceinline__ float2 csub(float2 a, float2 b){ return make_float2(a.x-b.x, a.y-b.y); }
__device__ __forceinline__ float2 cmul(float2 a, float2 b){
  return make_float2(fmaf(a.x,b.x,-a.y*b.y), fmaf(a.x,b.y,a.y*b.x));
}
__device__ __forceinline__ float2 cmulj(float2 a, float si){  // a * (si*i)
  return make_float2(-si*a.y, si*a.x);
}
__device__ __forceinline__ float2 shflx(float2 v, int m){
  return make_float2(__shfl_xor(v.x, m, 64), __shfl_xor(v.y, m, 64));
}
__device__ __forceinline__ float2 shfll(float2 v, int l){
  return make_float2(__shfl(v.x, l, 64), __shfl(v.y, l, 64));
}
__device__ __forceinline__ int brev6(int x){ return (int)(__brev((u32)x) >> 26); }

// lane exchange by XOR mask M: DPP for 1/2, ds_swizzle for 4/8/16, shfl for 32
template<int M>
__device__ __forceinline__ float xl(float x){
  if constexpr (M == 32) {
    return __shfl_xor(x, 32, 64);
  } else if constexpr (M >= 4) {
    return __int_as_float(__builtin_amdgcn_ds_swizzle(__float_as_int(x), (M << 10) | 0x1F));
  } else {
    constexpr int ctrl = (M == 2) ? 0x4E : 0xB1;   // quad_perm [2,3,0,1] / [1,0,3,2]
    return __int_as_float(__builtin_amdgcn_update_dpp(0, __float_as_int(x), ctrl, 0xF, 0xF, true));
  }
}
template<int M>
__device__ __forceinline__ float2 xch2(float2 v){ return make_float2(xl<M>(v.x), xl<M>(v.y)); }

// ======== layout A: d = lane + 64r (row kernels) ========
struct Tw { float2 t128, t64, t32, t16, t8, t4; float si; };

__device__ __forceinline__ float2 mkTw(int e, float si){
  float a = (float)e * 0.0245436926f;   // 2*pi/256
  return make_float2(cosf(a), si*sinf(a));
}
__device__ __forceinline__ Tw make_tw(int lane, float si){
  Tw w; w.si = si;
  w.t128 = mkTw(lane, si);
  w.t64  = mkTw(2*lane, si);
  w.t32  = mkTw((lane&31)*4, si);
  w.t16  = mkTw((lane&15)*8, si);
  w.t8   = mkTw((lane&7)*16, si);
  w.t4   = mkTw((lane&3)*32, si);
  return w;
}

__device__ __forceinline__ float2 bfly_dif(float2 v, int h, float2 th, int lane){
  float2 p = shflx(v, h);
  float sx = (lane & h) ? -1.f : 1.f;
  float2 s = make_float2(fmaf(sx, v.x, p.x), fmaf(sx, v.y, p.y));
  if (lane & h) s = cmul(s, th);
  return s;
}
__device__ __forceinline__ float2 bfly_dit(float2 v, int h, float2 th, int lane){
  if (lane & h) v = cmul(v, th);
  float2 p = shflx(v, h);
  float sx = (lane & h) ? -1.f : 1.f;
  return make_float2(fmaf(sx, v.x, p.x), fmaf(sx, v.y, p.y));
}

__device__ __forceinline__ void fft256_dif(float2 v[4], int lane, const Tw& T){
  float2 t128b = cmulj(T.t128, T.si);
  { float2 a=v[0], b=v[2]; v[0]=cadd(a,b); v[2]=cmul(csub(a,b), T.t128);
    float2 c=v[1], d=v[3]; v[1]=cadd(c,d); v[3]=cmul(csub(c,d), t128b); }
  { float2 a=v[0], b=v[1]; v[0]=cadd(a,b); v[1]=cmul(csub(a,b), T.t64);
    float2 c=v[2], d=v[3]; v[2]=cadd(c,d); v[3]=cmul(csub(c,d), T.t64); }
#pragma unroll
  for (int r=0;r<4;++r) v[r]=bfly_dif(v[r],32,T.t32,lane);
#pragma unroll
  for (int r=0;r<4;++r) v[r]=bfly_dif(v[r],16,T.t16,lane);
#pragma unroll
  for (int r=0;r<4;++r) v[r]=bfly_dif(v[r],8,T.t8,lane);
#pragma unroll
  for (int r=0;r<4;++r) v[r]=bfly_dif(v[r],4,T.t4,lane);
#pragma unroll
  for (int r=0;r<4;++r){
    float2 p=shflx(v[r],2);
    float sx=(lane&2)?-1.f:1.f;
    float2 s=make_float2(fmaf(sx,v[r].x,p.x), fmaf(sx,v[r].y,p.y));
    if ((lane&3)==3) s=cmulj(s,T.si);
    v[r]=s;
  }
#pragma unroll
  for (int r=0;r<4;++r){
    float2 p=shflx(v[r],1);
    float sx=(lane&1)?-1.f:1.f;
    v[r]=make_float2(fmaf(sx,v[r].x,p.x), fmaf(sx,v[r].y,p.y));
  }
}

__device__ __forceinline__ void fft256_dit(float2 v[4], int lane, const Tw& T){
#pragma unroll
  for (int r=0;r<4;++r){
    float2 p=shflx(v[r],1);
    float sx=(lane&1)?-1.f:1.f;
    v[r]=make_float2(fmaf(sx,v[r].x,p.x), fmaf(sx,v[r].y,p.y));
  }
#pragma unroll
  for (int r=0;r<4;++r){
    float2 w=v[r];
    if ((lane&3)==3) w=cmulj(w,T.si);
    float2 p=shflx(w,2);
    float sx=(lane&2)?-1.f:1.f;
    v[r]=make_float2(fmaf(sx,w.x,p.x), fmaf(sx,w.y,p.y));
  }
#pragma unroll
  for (int r=0;r<4;++r) v[r]=bfly_dit(v[r],4,T.t4,lane);
#pragma unroll
  for (int r=0;r<4;++r) v[r]=bfly_dit(v[r],8,T.t8,lane);
#pragma unroll
  for (int r=0;r<4;++r) v[r]=bfly_dit(v[r],16,T.t16,lane);
#pragma unroll
  for (int r=0;r<4;++r) v[r]=bfly_dit(v[r],32,T.t32,lane);
  { v[1]=cmul(v[1],T.t64); float2 a=v[0]; v[0]=cadd(a,v[1]); v[1]=csub(a,v[1]);
    v[3]=cmul(v[3],T.t64); float2 c=v[2]; v[2]=cadd(c,v[3]); v[3]=csub(c,v[3]); }
  { v[2]=cmul(v[2],T.t128); v[3]=cmul(v[3], cmulj(T.t128,T.si));
    float2 a=v[0]; v[0]=cadd(a,v[2]); v[2]=csub(a,v[2]);
    float2 b=v[1]; v[1]=cadd(b,v[3]); v[3]=csub(b,v[3]); }
}

// ======== layout B: d = 4*lane + r (colmix; chain twiddles + LDS table) ========
template<int M>
__device__ __forceinline__ void difA_stage(float2 v4[4][4], const float2 tw[4], int lane){
#pragma unroll
  for (int r=0;r<4;++r){
#pragma unroll
    for (int cc=0;cc<4;++cc){
      float2 p = xch2<M>(v4[cc][r]);
      float sx = (lane & M) ? -1.f : 1.f;
      float2 t = make_float2(fmaf(sx, v4[cc][r].x, p.x), fmaf(sx, v4[cc][r].y, p.y));
      float2 tm = cmul(t, tw[r]);
      v4[cc][r] = (lane & M) ? tm : t;
    }
  }
}
template<int M>
__device__ __forceinline__ void ditC_stage(float2 v4[4][4], const float2 tw[4], int lane){
#pragma unroll
  for (int r=0;r<4;++r){
#pragma unroll
    for (int cc=0;cc<4;++cc){
      float2 w = v4[cc][r];
      float2 wm_ = make_float2(fmaf(w.x, tw[r].x,  w.y*tw[r].y),
                               fmaf(w.y, tw[r].x, -w.x*tw[r].y));
      float2 u = (lane & M) ? wm_ : w;
      float2 p = xch2<M>(u);
      float sx = (lane & M) ? -1.f : 1.f;
      v4[cc][r] = make_float2(fmaf(sx, u.x, p.x), fmaf(sx, u.y, p.y));
    }
  }
}
__device__ __forceinline__ void tw_advance(float2 tw[4], int e[4]){
#pragma unroll
  for (int r=0;r<4;++r){
    float2 sq = cmul(tw[r], tw[r]);
    if (e[r] & 64) { sq.x = -sq.x; sq.y = -sq.y; }
    e[r] = (2*e[r]) & 127;
    tw[r] = sq;
  }
}

__device__ __forceinline__ int stage_row(int kw){ return 33*(kw&3) + (kw>>2); }
__device__ __forceinline__ int dslot(int n){ return (((n>>2)&7) ^ ((n&3)<<1)) << 4; }

// ---------------- Pass 1: row rfft, 2 real rows per complex FFT ----------------
__global__ __launch_bounds__(256) void k_rowfft(const float* __restrict__ x, u32* __restrict__ F) {
  __shared__ u32 stage[131*65];
  const int bc = blockIdx.x >> 2, hc = blockIdx.x & 3;
  const int tid = threadIdx.x, wave = tid >> 6, lane = tid & 63;
  Tw T = make_tw(lane, -1.f);
  const int L = brev6(lane);
  const int laneP0 = brev6((64 - L) & 63);
  const int lanePX = 63 - lane;

  float cx0[4], cx1[4];
  {
    const float* xa = x + ((size_t)bc*256 + hc*64 + wave*16) * 256;
#pragma unroll
    for (int r=0;r<4;++r){ cx0[r]=xa[lane+64*r]; cx1[r]=xa[256+lane+64*r]; }
  }
#pragma unroll
  for (int rr = 0; rr < 8; ++rr) {
    const int hl0 = wave*16 + rr*2, hl1 = hl0 + 1;
    float nx0[4], nx1[4];
    if (rr < 7) {
      const float* xb = x + ((size_t)bc*256 + hc*64 + hl0 + 2) * 256;
#pragma unroll
      for (int r=0;r<4;++r){ nx0[r]=xb[lane+64*r]; nx1[r]=xb[256+lane+64*r]; }
    }
    float2 v[4];
#pragma unroll
    for (int r=0;r<4;++r) v[r] = make_float2(cx0[r], cx1[r]);
    fft256_dif(v, lane, T);
#define UNSCR(R, RP, C, LP) { \
      float2 z = v[R]; float2 p = shfll(v[RP], LP); \
      float2 A  = make_float2(0.5f*(z.x+p.x), 0.5f*(z.y-p.y)); \
      float2 Bv = make_float2(0.5f*(z.y+p.y), 0.5f*(p.x-z.x)); \
      int kw = 4*L + (C); \
      if (kw <= 128) { int row = stage_row(kw); \
        stage[row*65 + hl0] = pack_bf16(A.x, A.y); \
        stage[row*65 + hl1] = pack_bf16(Bv.x, Bv.y); } }
    UNSCR(0, 0, 0, laneP0)
    UNSCR(1, 1, 2, lanePX)
    UNSCR(2, 3, 1, lanePX)
    UNSCR(3, 2, 3, lanePX)
#undef UNSCR
    if (rr < 7) {
#pragma unroll
      for (int r=0;r<4;++r){ cx0[r]=nx0[r]; cx1[r]=nx1[r]; }
    }
  }
  __syncthreads();
  for (int idx = tid; idx < 129*64; idx += 256) {
    int kw = idx >> 6, hl = idx & 63;
    F[((size_t)bc*129 + kw)*256 + hc*64 + hl] = stage[stage_row(kw)*65 + hl];
  }
}

// ---------------- Weight prep ----------------
__global__ __launch_bounds__(256) void k_prep_w(const float2* __restrict__ w1,
                                                const float2* __restrict__ w2,
                                                u32* __restrict__ Wt) {
  const int blk = blockIdx.x;      // k*2 + layer
  const int k = blk >> 1, layer = blk & 1;
  const float2* w = (layer == 0 ? w1 : w2) + (size_t)k * 96 * 96;
  u32* out = Wt + (size_t)blk * 18432;
  for (int idx = threadIdx.x; idx < 9216; idx += 256) {
    int o = idx % 96, i = idx / 96;
    float2 v = w[i * 96 + o];
    out[(2 * o) * 96 + i]     = pack_bf16(v.x, -v.y);
    out[(2 * o + 1) * 96 + i] = pack_bf16(v.y, v.x);
  }
}

// ---------------- Fused pass: colFFT + MFMA mix + inv colFFT, per (b,k,kw) -------
// 512 thr / 8 waves (2 wm x 4 wn). LDS (111360 B):
//   [0, 98304):      Dlds[n=0..255][kk=0..191] bf16, byte = n*384 + kk*2 ^ dslot(n)
//   [0, 99072):      Clds[c=0..95][n] u32 (phase C staging; overlaps Dlds)
//   [99072, 111360): Tlds[24][64] float2 forward twiddles (s*4+r major, lane minor)
#define CM_LDS_BYTES 111360
#define TLDS_OFF     99072

__global__ __launch_bounds__(512, 2) void k_colmix(u32* __restrict__ F,
    const u32* __restrict__ Wt,
    const float2* __restrict__ b1, const float2* __restrict__ b2) {
  extern __shared__ char smem[];
  float2* Tlds = reinterpret_cast<float2*>(smem + TLDS_OFF);

  const int bi = (blockIdx.x & 7) * 258 + (blockIdx.x >> 3);  // XCD swizzle (2064 = 8*258)
  const int kw = bi % 129;
  const int bk = bi / 129;
  const int k = bk & 7, b = bk >> 3;
  const int t = threadIdx.x;
  const int lane = t & 63, wave = t >> 6;
  const int wm = wave >> 2, wn = wave & 3;   // M = 2x96, N = 4x64
  const int lrow = lane & 15;
  const int g = lane >> 4;

  const size_t chstride = 129 * 256;
  const size_t colbase = (((size_t)(b*768 + k*96)) * 129 + kw) * 256;

  // ---- phase A: 12 cols/wave, prefetch 1 batch ahead; fwd FFT ----
  // batch 0: squaring-chain twiddles (recorded by ALL waves, identical values);
  // batches 1,2: twiddles re-read from Tlds (saves 4 sincos + 20 cmul per batch).
  {
    const float s = 1.f/256.f;
    uint4 cur[4];
#pragma unroll
    for (int cc = 0; cc < 4; ++cc)
      cur[cc] = *reinterpret_cast<const uint4*>(F + colbase + (size_t)(wave*12 + cc)*chstride + 4*lane);
#pragma unroll
    for (int bt = 0; bt < 3; ++bt) {
      uint4 nxt[4];
      if (bt < 2) {
#pragma unroll
        for (int cc = 0; cc < 4; ++cc)
          nxt[cc] = *reinterpret_cast<const uint4*>(F + colbase + (size_t)(wave*12 + (bt+1)*4 + cc)*chstride + 4*lane);
      }
      const int c0 = wave*12 + bt*4;
      float2 v4[4][4];
#pragma unroll
      for (int cc = 0; cc < 4; ++cc) {
        v4[cc][0]=unpack_bf16(cur[cc].x); v4[cc][1]=unpack_bf16(cur[cc].y);
        v4[cc][2]=unpack_bf16(cur[cc].z); v4[cc][3]=unpack_bf16(cur[cc].w);
      }
      if (bt == 0) {
        float2 tw[4]; int e[4];
#pragma unroll
        for (int r=0;r<4;++r){
          e[r] = (4*lane + r) & 127;
          float sn, cs;
          sincosf(-(float)e[r]*0.0245436926f, &sn, &cs);   // forward si = -1
          tw[r] = make_float2(cs, sn);
        }
#define A_STAGE0(M, SIDX) \
        { _Pragma("unroll") for (int r=0;r<4;++r) Tlds[((SIDX)*4+r)*64 + lane] = tw[r]; \
          difA_stage<M>(v4, tw, lane); \
          if ((SIDX) < 5) tw_advance(tw, e); }
        A_STAGE0(32,0) A_STAGE0(16,1) A_STAGE0(8,2) A_STAGE0(4,3) A_STAGE0(2,4) A_STAGE0(1,5)
#undef A_STAGE0
      } else {
        float2 tw[4];
#define A_STAGE1(M, SIDX) \
        { _Pragma("unroll") for (int r=0;r<4;++r) tw[r] = Tlds[((SIDX)*4+r)*64 + lane]; \
          difA_stage<M>(v4, tw, lane); }
        A_STAGE1(32,0) A_STAGE1(16,1) A_STAGE1(8,2) A_STAGE1(4,3) A_STAGE1(2,4) A_STAGE1(1,5)
#undef A_STAGE1
      }
#pragma unroll
      for (int cc = 0; cc < 4; ++cc) {
        float2* v = v4[cc];
        { float2 a0=v[0], a2=v[2]; v[0]=cadd(a0,a2); v[2]=csub(a0,a2);
          float2 a1=v[1], a3=v[3]; v[1]=cadd(a1,a3); v[3]=cmulj(csub(a1,a3), -1.f); }
        { float2 a=v[0]; v[0]=cadd(a,v[1]); v[1]=csub(a,v[1]);
          float2 c=v[2]; v[2]=cadd(c,v[3]); v[3]=csub(c,v[3]); }
      }
#pragma unroll
      for (int r = 0; r < 4; ++r) {
        int n = 4*lane + r;
        int byte = (n*384 + c0*4) ^ dslot(n);
        uint4 w;
        w.x = pack_bf16(v4[0][r].x*s, v4[0][r].y*s);
        w.y = pack_bf16(v4[1][r].x*s, v4[1][r].y*s);
        w.z = pack_bf16(v4[2][r].x*s, v4[2][r].y*s);
        w.w = pack_bf16(v4[3][r].x*s, v4[3][r].y*s);
        *reinterpret_cast<uint4*>(smem + byte) = w;
      }
      if (bt < 2) {
#pragma unroll
        for (int cc = 0; cc < 4; ++cc) cur[cc] = nxt[cc];
      }
    }
  }
  __syncthreads();

  const bf16x8* W1v = reinterpret_cast<const bf16x8*>(Wt + (size_t)(k*2 + 0) * 18432);
  const bf16x8* W2v = reinterpret_cast<const bf16x8*>(Wt + (size_t)(k*2 + 1) * 18432);

  f32x4 acc[6][4];   // 96 VGPRs

  // ---- layer 1: acc = W1 x D  (bf[4] per ks; af 2-deep pipeline) ----
#pragma unroll
  for (int mi = 0; mi < 6; ++mi)
#pragma unroll
    for (int ni = 0; ni < 4; ++ni) acc[mi][ni] = (f32x4)0.f;
#pragma unroll
  for (int ks = 0; ks < 6; ++ks) {
    bf16x8 bf[4];
#pragma unroll
    for (int ni = 0; ni < 4; ++ni) {
      int n = wn*64 + ni*16 + lrow;
      bf[ni] = *reinterpret_cast<bf16x8*>(smem + ((n*384 + ks*64 + g*16) ^ dslot(n)));
    }
    bf16x8 af0 = W1v[(wm*96 + 0*16 + lrow)*24 + ks*4 + g];
#pragma unroll
    for (int mi = 0; mi < 6; ++mi) {
      bf16x8 afn;
      if (mi < 5) afn = W1v[(wm*96 + (mi+1)*16 + lrow)*24 + ks*4 + g];
#pragma unroll
      for (int ni = 0; ni < 4; ++ni)
        acc[mi][ni] = __builtin_amdgcn_mfma_f32_16x16x32_bf16(af0, bf[ni], acc[mi][ni], 0, 0, 0);
      af0 = afn;
    }
  }
  __syncthreads();

  // ---- O1 = relu(acc + b1) -> Dlds in place ----
  {
    const float2* b1k = b1 + k * 96;
#pragma unroll
    for (int mi = 0; mi < 6; ++mi) {
      int m0 = wm*96 + mi*16 + 4*g;
      int o0 = m0 >> 1;
      float2 ba = b1k[o0], bb = b1k[o0 + 1];
#pragma unroll
      for (int ni = 0; ni < 4; ++ni) {
        int n = wn*64 + ni*16 + lrow;
        f32x4 v = acc[mi][ni];
        u32 lo = pack_bf16(fmaxf(v[0] + ba.x, 0.f), fmaxf(v[1] + ba.y, 0.f));
        u32 hi = pack_bf16(fmaxf(v[2] + bb.x, 0.f), fmaxf(v[3] + bb.y, 0.f));
        int byte = (n*384 + m0*2) ^ dslot(n);
        *reinterpret_cast<uint2*>(smem + byte) = make_uint2(lo, hi);
      }
    }
  }
  __syncthreads();

  // ---- layer 2: acc = W2 x O1 ----
#pragma unroll
  for (int mi = 0; mi < 6; ++mi)
#pragma unroll
    for (int ni = 0; ni < 4; ++ni) acc[mi][ni] = (f32x4)0.f;
#pragma unroll
  for (int ks = 0; ks < 6; ++ks) {
    bf16x8 bf[4];
#pragma unroll
    for (int ni = 0; ni < 4; ++ni) {
      int n = wn*64 + ni*16 + lrow;
      bf[ni] = *reinterpret_cast<bf16x8*>(smem + ((n*384 + ks*64 + g*16) ^ dslot(n)));
    }
    bf16x8 af0 = W2v[(wm*96 + 0*16 + lrow)*24 + ks*4 + g];
#pragma unroll
    for (int mi = 0; mi < 6; ++mi) {
      bf16x8 afn;
      if (mi < 5) afn = W2v[(wm*96 + (mi+1)*16 + lrow)*24 + ks*4 + g];
#pragma unroll
      for (int ni = 0; ni < 4; ++ni)
        acc[mi][ni] = __builtin_amdgcn_mfma_f32_16x16x32_bf16(af0, bf[ni], acc[mi][ni], 0, 0, 0);
      af0 = afn;
    }
  }
  __syncthreads();

  // ---- epilogue: bias2 + softshrink -> Clds [c][n] (dword = c*258 + n) ----
  {
    u32* Clds = reinterpret_cast<u32*>(smem);
    const float2* b2k = b2 + k * 96;
#pragma unroll
    for (int mi = 0; mi < 6; ++mi) {
      int m0 = wm*96 + mi*16 + 4*g;
      int o0 = m0 >> 1;
      float2 ca = b2k[o0], cb = b2k[o0 + 1];
#pragma unroll
      for (int ni = 0; ni < 4; ++ni) {
        int n = wn*64 + ni*16 + lrow;
        f32x4 v = acc[mi][ni];
        Clds[o0*258 + n]       = pack_bf16(sshrink(v[0] + ca.x), sshrink(v[1] + ca.y));
        Clds[(o0 + 1)*258 + n] = pack_bf16(sshrink(v[2] + cb.x), sshrink(v[3] + cb.y));
      }
    }
  }
  __syncthreads();

  // ---- phase C: inverse FFT, twiddles from Tlds (conjugated), uint4 stores ----
  {
    const u32* Clds = reinterpret_cast<const u32*>(smem);
    const float s = 1.f/256.f;
#pragma unroll
    for (int bt = 0; bt < 3; ++bt) {
      const int c0 = wave*12 + bt*4;
      float2 v4[4][4];
#pragma unroll
      for (int cc = 0; cc < 4; ++cc) {
        uint2 q0 = *reinterpret_cast<const uint2*>(Clds + (c0+cc)*258 + 4*lane);
        uint2 q1 = *reinterpret_cast<const uint2*>(Clds + (c0+cc)*258 + 4*lane + 2);
        v4[cc][0]=unpack_bf16(q0.x); v4[cc][1]=unpack_bf16(q0.y);
        v4[cc][2]=unpack_bf16(q1.x); v4[cc][3]=unpack_bf16(q1.y);
      }
#pragma unroll
      for (int cc = 0; cc < 4; ++cc) {
        float2* v = v4[cc];
        { float2 a=v[0]; v[0]=cadd(a,v[1]); v[1]=csub(a,v[1]);
          float2 c=v[2]; v[2]=cadd(c,v[3]); v[3]=csub(c,v[3]); }
        { v[3] = cmulj(v[3], 1.f);
          float2 a0=v[0]; v[0]=cadd(a0,v[2]); v[2]=csub(a0,v[2]);
          float2 a1=v[1]; v[1]=cadd(a1,v[3]); v[3]=csub(a1,v[3]); }
      }
      float2 tw[4];
#define C_STAGE(M, SIDX) \
      { _Pragma("unroll") for (int r=0;r<4;++r) tw[r] = Tlds[((SIDX)*4+r)*64 + lane]; \
        ditC_stage<M>(v4, tw, lane); }
      C_STAGE(1,5) C_STAGE(2,4) C_STAGE(4,3) C_STAGE(8,2) C_STAGE(16,1) C_STAGE(32,0)
#undef C_STAGE
#pragma unroll
      for (int cc = 0; cc < 4; ++cc) {
        uint4 o;
        o.x = pack_bf16(v4[cc][0].x*s, v4[cc][0].y*s);
        o.y = pack_bf16(v4[cc][1].x*s, v4[cc][1].y*s);
        o.z = pack_bf16(v4[cc][2].x*s, v4[cc][2].y*s);
        o.w = pack_bf16(v4[cc][3].x*s, v4[cc][3].y*s);
        *reinterpret_cast<uint4*>(F + colbase + (size_t)(c0+cc)*chstride + 4*lane) = o;
      }
    }
  }
}

// ---------------- Pass 5: row irfft (Hermitian ext), 2 rows per FFT, + bias ------
__global__ __launch_bounds__(256) void k_rowifft(const u32* __restrict__ F,
                                                 const float* __restrict__ x,
                                                 float* __restrict__ out) {
  __shared__ u32 stage[131*65];
  const int bc = blockIdx.x >> 2, hc = blockIdx.x & 3;
  const int tid = threadIdx.x, wave = tid >> 6, lane = tid & 63;
  Tw T = make_tw(lane, 1.f);
  for (int idx = tid; idx < 129*64; idx += 256) {
    int kw = idx >> 6, hl = idx & 63;
    stage[stage_row(kw)*65 + hl] = F[((size_t)bc*129 + kw)*256 + hc*64 + hl];
  }
  __syncthreads();

  const int L = brev6(lane);
#pragma unroll
  for (int rr = 0; rr < 8; ++rr) {
    const int hl0 = wave*16 + rr*2, hl1 = hl0 + 1;
    const float* xa = x + ((size_t)bc*256 + hc*64 + hl0) * 256;
    float xv0[4], xv1[4];
#pragma unroll
    for (int r=0;r<4;++r){ xv0[r]=xa[lane+64*r]; xv1[r]=xa[256+lane+64*r]; }
    float2 v[4];
#pragma unroll
    for (int r=0;r<4;++r) {
      int c = ((r&1)<<1) | (r>>1);
      int kw = 4*L + c;
      int src = (kw <= 128) ? kw : 256 - kw;
      float sg = (kw <= 128) ? 1.f : -1.f;
      int row = stage_row(src);
      float2 a = unpack_bf16(stage[row*65 + hl0]);
      float2 b = unpack_bf16(stage[row*65 + hl1]);
      a.y *= sg; b.y *= sg;
      if (kw == 0 || kw == 128) { a.y = 0.f; b.y = 0.f; }
      v[r] = make_float2(a.x - b.y, a.y + b.x);
    }
    fft256_dit(v, lane, T);
    float* oa = out + ((size_t)bc*256 + hc*64 + hl0) * 256;
#pragma unroll
    for (int r=0;r<4;++r) {
      int d = lane + 64*r;
      oa[d]       = v[r].x + xv0[r];
      oa[256 + d] = v[r].y + xv1[r];
    }
  }
}

extern "C" void kernel_launch(void* const* d_in, const int* in_sizes, int n_in,
                              void* d_out, int out_size, void* d_ws, size_t ws_size,
                              hipStream_t stream) {
  const float* x   = (const float*)d_in[0];
  const float2* w1 = (const float2*)d_in[1];
  const float2* b1 = (const float2*)d_in[2];
  const float2* w2 = (const float2*)d_in[3];
  const float2* b2 = (const float2*)d_in[4];
  float* out = (float*)d_out;
  u32* F = (u32*)d_ws;            // 1536*129*256*4 B ~ 203 MB
  u32* Wt = (u32*)d_out;          // d_out head as scratch; overwritten by k_rowifft

  (void)hipFuncSetAttribute(reinterpret_cast<const void*>(k_colmix),
                            hipFuncAttributeMaxDynamicSharedMemorySize, CM_LDS_BYTES);

  const int n_rows_blocks = 1536 * 4;
  const int n_cm_blocks   = 2 * 8 * 129;   // 2064 = 8 * 258

  k_prep_w<<<16, 256, 0, stream>>>(w1, w2, Wt);
  k_rowfft<<<n_rows_blocks, 256, 0, stream>>>(x, F);
  k_colmix<<<n_cm_blocks, 512, CM_LDS_BYTES, stream>>>(F, Wt, b1, b2);
  k_rowifft<<<n_rows_blocks, 256, 0, stream>>>(F, x, out);
}

// Round 17
// 779.614 us; speedup vs baseline: 1.0741x; 1.0080x over previous
//
#include <hip/hip_runtime.h>
#include <hip/hip_bf16.h>
#include <math.h>

// DistributedAFNO2D: out = x + irfft2( blockMLP( rfft2(x, ortho) ), ortho )
// B=2, C=768, H=W=256, 8 blocks x 96 ch, KW = 129 frequency cols.
// F in d_ws: bf16-packed complex (u32 = [imag:bf16 | real:bf16]), layout (B*C, KW, H).
// Passes: rowfft -> [fused: colFFT + MFMA mix + inv colFFT] -> rowifft.
// colmix: 512 thr / 128 VGPRs. Round 17: stage-4/5 twiddles are closed-form
// (stage5 lane-independent W^{32r}; stage4 = W^{16r} * (lane&1 ? -i : 1)) ->
// no LDS traffic for them; Tlds holds only stages 0-3 (8KB); phase C hoists
// those 16 twiddles to registers once (removes 72 serialized ds_read_b64).

#define LAMBDA_SS 0.01f

typedef unsigned int u32;
typedef __attribute__((ext_vector_type(8))) short bf16x8;
typedef __attribute__((ext_vector_type(4))) float f32x4;

__device__ __forceinline__ u32 pack_bf16(float r, float i) {
  union { __hip_bfloat162 h; u32 u; } cv;
  cv.h = __float22bfloat162_rn(make_float2(r, i));   // v_cvt_pk_bf16_f32
  return cv.u;
}

__device__ __forceinline__ float2 unpack_bf16(u32 p) {
  union { u32 u; float f; } a, b;
  a.u = (p & 0xFFFFu) << 16;
  b.u = (p & 0xFFFF0000u);
  return make_float2(a.f, b.f);
}

__device__ __forceinline__ float sshrink(float v) {
  return (v > LAMBDA_SS) ? v - LAMBDA_SS : ((v < -LAMBDA_SS) ? v + LAMBDA_SS : 0.f);
}

// ---------------- register FFT machinery (shared helpers) ----------------
__device__ __forceinline__ float2 cadd(float2 a, float2 b){ return make_float2(a.x+b.x, a.y+b.y); }
__device__ __forceinline__ float2 csub(float2 a, float2 b){ return make_float2(a.x-b.x, a.y-b.y); }
__device__ __forceinline__ float2 cmul(float2 a, float2 b){
  return make_float2(fmaf(a.x,b.x,-a.y*b.y), fmaf(a.x,b.y,a.y*b.x));
}
__device__ __forceinline__ float2 cmulj(float2 a, float si){  // a * (si*i)
  return make_float2(-si*a.y, si*a.x);
}
__device__ __forceinline__ float2 shflx(float2 v, int m){
  return make_float2(__shfl_xor(v.x, m, 64), __shfl_xor(v.y, m, 64));
}
__device__ __forceinline__ float2 shfll(float2 v, int l){
  return make_float2(__shfl(v.x, l, 64), __shfl(v.y, l, 64));
}
__device__ __forceinline__ int brev6(int x){ return (int)(__brev((u32)x) >> 26); }

// lane exchange by XOR mask M: DPP for 1/2, ds_swizzle for 4/8/16, shfl for 32
template<int M>
__device__ __forceinline__ float xl(float x){
  if constexpr (M == 32) {
    return __shfl_xor(x, 32, 64);
  } else if constexpr (M >= 4) {
    return __int_as_float(__builtin_amdgcn_ds_swizzle(__float_as_int(x), (M << 10) | 0x1F));
  } else {
    constexpr int ctrl = (M == 2) ? 0x4E : 0xB1;   // quad_perm [2,3,0,1] / [1,0,3,2]
    return __int_as_float(__builtin_amdgcn_update_dpp(0, __float_as_int(x), ctrl, 0xF, 0xF, true));
  }
}
template<int M>
__device__ __forceinline__ float2 xch2(float2 v){ return make_float2(xl<M>(v.x), xl<M>(v.y)); }

// ======== layout A: d = lane + 64r (row kernels) ========
struct Tw { float2 t128, t64, t32, t16, t8, t4; float si; };

__device__ __forceinline__ float2 mkTw(int e, float si){
  float a = (float)e * 0.0245436926f;   // 2*pi/256
  return make_float2(cosf(a), si*sinf(a));
}
__device__ __forceinline__ Tw make_tw(int lane, float si){
  Tw w; w.si = si;
  w.t128 = mkTw(lane, si);
  w.t64  = mkTw(2*lane, si);
  w.t32  = mkTw((lane&31)*4, si);
  w.t16  = mkTw((lane&15)*8, si);
  w.t8   = mkTw((lane&7)*16, si);
  w.t4   = mkTw((lane&3)*32, si);
  return w;
}

__device__ __forceinline__ float2 bfly_dif(float2 v, int h, float2 th, int lane){
  float2 p = shflx(v, h);
  float sx = (lane & h) ? -1.f : 1.f;
  float2 s = make_float2(fmaf(sx, v.x, p.x), fmaf(sx, v.y, p.y));
  if (lane & h) s = cmul(s, th);
  return s;
}
__device__ __forceinline__ float2 bfly_dit(float2 v, int h, float2 th, int lane){
  if (lane & h) v = cmul(v, th);
  float2 p = shflx(v, h);
  float sx = (lane & h) ? -1.f : 1.f;
  return make_float2(fmaf(sx, v.x, p.x), fmaf(sx, v.y, p.y));
}

__device__ __forceinline__ void fft256_dif(float2 v[4], int lane, const Tw& T){
  float2 t128b = cmulj(T.t128, T.si);
  { float2 a=v[0], b=v[2]; v[0]=cadd(a,b); v[2]=cmul(csub(a,b), T.t128);
    float2 c=v[1], d=v[3]; v[1]=cadd(c,d); v[3]=cmul(csub(c,d), t128b); }
  { float2 a=v[0], b=v[1]; v[0]=cadd(a,b); v[1]=cmul(csub(a,b), T.t64);
    float2 c=v[2], d=v[3]; v[2]=cadd(c,d); v[3]=cmul(csub(c,d), T.t64); }
#pragma unroll
  for (int r=0;r<4;++r) v[r]=bfly_dif(v[r],32,T.t32,lane);
#pragma unroll
  for (int r=0;r<4;++r) v[r]=bfly_dif(v[r],16,T.t16,lane);
#pragma unroll
  for (int r=0;r<4;++r) v[r]=bfly_dif(v[r],8,T.t8,lane);
#pragma unroll
  for (int r=0;r<4;++r) v[r]=bfly_dif(v[r],4,T.t4,lane);
#pragma unroll
  for (int r=0;r<4;++r){
    float2 p=shflx(v[r],2);
    float sx=(lane&2)?-1.f:1.f;
    float2 s=make_float2(fmaf(sx,v[r].x,p.x), fmaf(sx,v[r].y,p.y));
    if ((lane&3)==3) s=cmulj(s,T.si);
    v[r]=s;
  }
#pragma unroll
  for (int r=0;r<4;++r){
    float2 p=shflx(v[r],1);
    float sx=(lane&1)?-1.f:1.f;
    v[r]=make_float2(fmaf(sx,v[r].x,p.x), fmaf(sx,v[r].y,p.y));
  }
}

__device__ __forceinline__ void fft256_dit(float2 v[4], int lane, const Tw& T){
#pragma unroll
  for (int r=0;r<4;++r){
    float2 p=shflx(v[r],1);
    float sx=(lane&1)?-1.f:1.f;
    v[r]=make_float2(fmaf(sx,v[r].x,p.x), fmaf(sx,v[r].y,p.y));
  }
#pragma unroll
  for (int r=0;r<4;++r){
    float2 w=v[r];
    if ((lane&3)==3) w=cmulj(w,T.si);
    float2 p=shflx(w,2);
    float sx=(lane&2)?-1.f:1.f;
    v[r]=make_float2(fmaf(sx,w.x,p.x), fmaf(sx,w.y,p.y));
  }
#pragma unroll
  for (int r=0;r<4;++r) v[r]=bfly_dit(v[r],4,T.t4,lane);
#pragma unroll
  for (int r=0;r<4;++r) v[r]=bfly_dit(v[r],8,T.t8,lane);
#pragma unroll
  for (int r=0;r<4;++r) v[r]=bfly_dit(v[r],16,T.t16,lane);
#pragma unroll
  for (int r=0;r<4;++r) v[r]=bfly_dit(v[r],32,T.t32,lane);
  { v[1]=cmul(v[1],T.t64); float2 a=v[0]; v[0]=cadd(a,v[1]); v[1]=csub(a,v[1]);
    v[3]=cmul(v[3],T.t64); float2 c=v[2]; v[2]=cadd(c,v[3]); v[3]=csub(c,v[3]); }
  { v[2]=cmul(v[2],T.t128); v[3]=cmul(v[3], cmulj(T.t128,T.si));
    float2 a=v[0]; v[0]=cadd(a,v[2]); v[2]=csub(a,v[2]);
    float2 b=v[1]; v[1]=cadd(b,v[3]); v[3]=csub(b,v[3]); }
}

// ======== layout B: d = 4*lane + r (colmix; chain twiddles + LDS table) ========
template<int M>
__device__ __forceinline__ void difA_stage(float2 v4[4][4], const float2 tw[4], int lane){
#pragma unroll
  for (int r=0;r<4;++r){
#pragma unroll
    for (int cc=0;cc<4;++cc){
      float2 p = xch2<M>(v4[cc][r]);
      float sx = (lane & M) ? -1.f : 1.f;
      float2 t = make_float2(fmaf(sx, v4[cc][r].x, p.x), fmaf(sx, v4[cc][r].y, p.y));
      float2 tm = cmul(t, tw[r]);
      v4[cc][r] = (lane & M) ? tm : t;
    }
  }
}
template<int M>
__device__ __forceinline__ void ditC_stage(float2 v4[4][4], const float2 tw[4], int lane){
#pragma unroll
  for (int r=0;r<4;++r){
#pragma unroll
    for (int cc=0;cc<4;++cc){
      float2 w = v4[cc][r];
      float2 wm_ = make_float2(fmaf(w.x, tw[r].x,  w.y*tw[r].y),
                               fmaf(w.y, tw[r].x, -w.x*tw[r].y));
      float2 u = (lane & M) ? wm_ : w;
      float2 p = xch2<M>(u);
      float sx = (lane & M) ? -1.f : 1.f;
      v4[cc][r] = make_float2(fmaf(sx, u.x, p.x), fmaf(sx, u.y, p.y));
    }
  }
}
__device__ __forceinline__ void tw_advance(float2 tw[4], int e[4]){
#pragma unroll
  for (int r=0;r<4;++r){
    float2 sq = cmul(tw[r], tw[r]);
    if (e[r] & 64) { sq.x = -sq.x; sq.y = -sq.y; }
    e[r] = (2*e[r]) & 127;
    tw[r] = sq;
  }
}

// closed-form forward twiddles (si = -1) for stages 4 (mask 2) and 5 (mask 1):
//   stage5: e = 32r (lane-independent);  stage4: e = 64*(lane&1) + 16r
#define RT2 0.70710678118654752f
#define C16F 0.92387953251128676f
#define S16F 0.38268343236508977f
__device__ __forceinline__ void make_tw45(int lane, float2 tw4[4], float2 tw5[4]){
  tw5[0] = make_float2(1.f, 0.f);
  tw5[1] = make_float2(RT2, -RT2);
  tw5[2] = make_float2(0.f, -1.f);
  tw5[3] = make_float2(-RT2, -RT2);
  float2 b0 = make_float2(1.f, 0.f);
  float2 b1 = make_float2(C16F, -S16F);
  float2 b2 = make_float2(RT2, -RT2);
  float2 b3 = make_float2(S16F, -C16F);
  if (lane & 1) {   // multiply by W^64 = -i: (x,y) -> (y,-x)
    tw4[0] = make_float2(b0.y, -b0.x); tw4[1] = make_float2(b1.y, -b1.x);
    tw4[2] = make_float2(b2.y, -b2.x); tw4[3] = make_float2(b3.y, -b3.x);
  } else {
    tw4[0] = b0; tw4[1] = b1; tw4[2] = b2; tw4[3] = b3;
  }
}

__device__ __forceinline__ int stage_row(int kw){ return 33*(kw&3) + (kw>>2); }
__device__ __forceinline__ int dslot(int n){ return (((n>>2)&7) ^ ((n&3)<<1)) << 4; }

// ---------------- Pass 1: row rfft, 2 real rows per complex FFT ----------------
__global__ __launch_bounds__(256) void k_rowfft(const float* __restrict__ x, u32* __restrict__ F) {
  __shared__ u32 stage[131*65];
  const int bc = blockIdx.x >> 2, hc = blockIdx.x & 3;
  const int tid = threadIdx.x, wave = tid >> 6, lane = tid & 63;
  Tw T = make_tw(lane, -1.f);
  const int L = brev6(lane);
  const int laneP0 = brev6((64 - L) & 63);
  const int lanePX = 63 - lane;

  float cx0[4], cx1[4];
  {
    const float* xa = x + ((size_t)bc*256 + hc*64 + wave*16) * 256;
#pragma unroll
    for (int r=0;r<4;++r){ cx0[r]=xa[lane+64*r]; cx1[r]=xa[256+lane+64*r]; }
  }
#pragma unroll
  for (int rr = 0; rr < 8; ++rr) {
    const int hl0 = wave*16 + rr*2, hl1 = hl0 + 1;
    float nx0[4], nx1[4];
    if (rr < 7) {
      const float* xb = x + ((size_t)bc*256 + hc*64 + hl0 + 2) * 256;
#pragma unroll
      for (int r=0;r<4;++r){ nx0[r]=xb[lane+64*r]; nx1[r]=xb[256+lane+64*r]; }
    }
    float2 v[4];
#pragma unroll
    for (int r=0;r<4;++r) v[r] = make_float2(cx0[r], cx1[r]);
    fft256_dif(v, lane, T);
#define UNSCR(R, RP, C, LP) { \
      float2 z = v[R]; float2 p = shfll(v[RP], LP); \
      float2 A  = make_float2(0.5f*(z.x+p.x), 0.5f*(z.y-p.y)); \
      float2 Bv = make_float2(0.5f*(z.y+p.y), 0.5f*(p.x-z.x)); \
      int kw = 4*L + (C); \
      if (kw <= 128) { int row = stage_row(kw); \
        stage[row*65 + hl0] = pack_bf16(A.x, A.y); \
        stage[row*65 + hl1] = pack_bf16(Bv.x, Bv.y); } }
    UNSCR(0, 0, 0, laneP0)
    UNSCR(1, 1, 2, lanePX)
    UNSCR(2, 3, 1, lanePX)
    UNSCR(3, 2, 3, lanePX)
#undef UNSCR
    if (rr < 7) {
#pragma unroll
      for (int r=0;r<4;++r){ cx0[r]=nx0[r]; cx1[r]=nx1[r]; }
    }
  }
  __syncthreads();
  for (int idx = tid; idx < 129*64; idx += 256) {
    int kw = idx >> 6, hl = idx & 63;
    F[((size_t)bc*129 + kw)*256 + hc*64 + hl] = stage[stage_row(kw)*65 + hl];
  }
}

// ---------------- Weight prep ----------------
__global__ __launch_bounds__(256) void k_prep_w(const float2* __restrict__ w1,
                                                const float2* __restrict__ w2,
                                                u32* __restrict__ Wt) {
  const int blk = blockIdx.x;      // k*2 + layer
  const int k = blk >> 1, layer = blk & 1;
  const float2* w = (layer == 0 ? w1 : w2) + (size_t)k * 96 * 96;
  u32* out = Wt + (size_t)blk * 18432;
  for (int idx = threadIdx.x; idx < 9216; idx += 256) {
    int o = idx % 96, i = idx / 96;
    float2 v = w[i * 96 + o];
    out[(2 * o) * 96 + i]     = pack_bf16(v.x, -v.y);
    out[(2 * o + 1) * 96 + i] = pack_bf16(v.y, v.x);
  }
}

// ---------------- Fused pass: colFFT + MFMA mix + inv colFFT, per (b,k,kw) -------
// 512 thr / 8 waves (2 wm x 4 wn). LDS (107264 B):
//   [0, 98304):      Dlds[n=0..255][kk=0..191] bf16, byte = n*384 + kk*2 ^ dslot(n)
//   [0, 99072):      Clds[c=0..95][n] u32 (phase C staging; overlaps Dlds)
//   [99072, 107264): Tlds[16][64] float2 forward twiddles, stages 0-3 only
#define CM_LDS_BYTES 107264
#define TLDS_OFF     99072

__global__ __launch_bounds__(512, 2) void k_colmix(u32* __restrict__ F,
    const u32* __restrict__ Wt,
    const float2* __restrict__ b1, const float2* __restrict__ b2) {
  extern __shared__ char smem[];
  float2* Tlds = reinterpret_cast<float2*>(smem + TLDS_OFF);

  const int bi = (blockIdx.x & 7) * 258 + (blockIdx.x >> 3);  // XCD swizzle (2064 = 8*258)
  const int kw = bi % 129;
  const int bk = bi / 129;
  const int k = bk & 7, b = bk >> 3;
  const int t = threadIdx.x;
  const int lane = t & 63, wave = t >> 6;
  const int wm = wave >> 2, wn = wave & 3;   // M = 2x96, N = 4x64
  const int lrow = lane & 15;
  const int g = lane >> 4;

  const size_t chstride = 129 * 256;
  const size_t colbase = (((size_t)(b*768 + k*96)) * 129 + kw) * 256;

  // ---- phase A: 12 cols/wave, prefetch 1 batch ahead; fwd FFT ----
  {
    const float s = 1.f/256.f;
    float2 tw4[4], tw5[4];
    make_tw45(lane, tw4, tw5);
    uint4 cur[4];
#pragma unroll
    for (int cc = 0; cc < 4; ++cc)
      cur[cc] = *reinterpret_cast<const uint4*>(F + colbase + (size_t)(wave*12 + cc)*chstride + 4*lane);
#pragma unroll
    for (int bt = 0; bt < 3; ++bt) {
      uint4 nxt[4];
      if (bt < 2) {
#pragma unroll
        for (int cc = 0; cc < 4; ++cc)
          nxt[cc] = *reinterpret_cast<const uint4*>(F + colbase + (size_t)(wave*12 + (bt+1)*4 + cc)*chstride + 4*lane);
      }
      const int c0 = wave*12 + bt*4;
      float2 v4[4][4];
#pragma unroll
      for (int cc = 0; cc < 4; ++cc) {
        v4[cc][0]=unpack_bf16(cur[cc].x); v4[cc][1]=unpack_bf16(cur[cc].y);
        v4[cc][2]=unpack_bf16(cur[cc].z); v4[cc][3]=unpack_bf16(cur[cc].w);
      }
      if (bt == 0) {
        float2 tw[4]; int e[4];
#pragma unroll
        for (int r=0;r<4;++r){
          e[r] = (4*lane + r) & 127;
          float sn, cs;
          sincosf(-(float)e[r]*0.0245436926f, &sn, &cs);   // forward si = -1
          tw[r] = make_float2(cs, sn);
        }
#define A_STAGE0(M, SIDX) \
        { _Pragma("unroll") for (int r=0;r<4;++r) Tlds[((SIDX)*4+r)*64 + lane] = tw[r]; \
          difA_stage<M>(v4, tw, lane); \
          if ((SIDX) < 3) tw_advance(tw, e); }
        A_STAGE0(32,0) A_STAGE0(16,1) A_STAGE0(8,2) A_STAGE0(4,3)
#undef A_STAGE0
      } else {
        float2 tw[4];
#define A_STAGE1(M, SIDX) \
        { _Pragma("unroll") for (int r=0;r<4;++r) tw[r] = Tlds[((SIDX)*4+r)*64 + lane]; \
          difA_stage<M>(v4, tw, lane); }
        A_STAGE1(32,0) A_STAGE1(16,1) A_STAGE1(8,2) A_STAGE1(4,3)
#undef A_STAGE1
      }
      difA_stage<2>(v4, tw4, lane);
      difA_stage<1>(v4, tw5, lane);
#pragma unroll
      for (int cc = 0; cc < 4; ++cc) {
        float2* v = v4[cc];
        { float2 a0=v[0], a2=v[2]; v[0]=cadd(a0,a2); v[2]=csub(a0,a2);
          float2 a1=v[1], a3=v[3]; v[1]=cadd(a1,a3); v[3]=cmulj(csub(a1,a3), -1.f); }
        { float2 a=v[0]; v[0]=cadd(a,v[1]); v[1]=csub(a,v[1]);
          float2 c=v[2]; v[2]=cadd(c,v[3]); v[3]=csub(c,v[3]); }
      }
#pragma unroll
      for (int r = 0; r < 4; ++r) {
        int n = 4*lane + r;
        int byte = (n*384 + c0*4) ^ dslot(n);
        uint4 w;
        w.x = pack_bf16(v4[0][r].x*s, v4[0][r].y*s);
        w.y = pack_bf16(v4[1][r].x*s, v4[1][r].y*s);
        w.z = pack_bf16(v4[2][r].x*s, v4[2][r].y*s);
        w.w = pack_bf16(v4[3][r].x*s, v4[3][r].y*s);
        *reinterpret_cast<uint4*>(smem + byte) = w;
      }
      if (bt < 2) {
#pragma unroll
        for (int cc = 0; cc < 4; ++cc) cur[cc] = nxt[cc];
      }
    }
  }
  __syncthreads();

  const bf16x8* W1v = reinterpret_cast<const bf16x8*>(Wt + (size_t)(k*2 + 0) * 18432);
  const bf16x8* W2v = reinterpret_cast<const bf16x8*>(Wt + (size_t)(k*2 + 1) * 18432);

  f32x4 acc[6][4];   // 96 VGPRs

  // ---- layer 1: acc = W1 x D  (bf[4] per ks; af 2-deep pipeline) ----
#pragma unroll
  for (int mi = 0; mi < 6; ++mi)
#pragma unroll
    for (int ni = 0; ni < 4; ++ni) acc[mi][ni] = (f32x4)0.f;
#pragma unroll
  for (int ks = 0; ks < 6; ++ks) {
    bf16x8 bf[4];
#pragma unroll
    for (int ni = 0; ni < 4; ++ni) {
      int n = wn*64 + ni*16 + lrow;
      bf[ni] = *reinterpret_cast<bf16x8*>(smem + ((n*384 + ks*64 + g*16) ^ dslot(n)));
    }
    bf16x8 af0 = W1v[(wm*96 + 0*16 + lrow)*24 + ks*4 + g];
#pragma unroll
    for (int mi = 0; mi < 6; ++mi) {
      bf16x8 afn;
      if (mi < 5) afn = W1v[(wm*96 + (mi+1)*16 + lrow)*24 + ks*4 + g];
#pragma unroll
      for (int ni = 0; ni < 4; ++ni)
        acc[mi][ni] = __builtin_amdgcn_mfma_f32_16x16x32_bf16(af0, bf[ni], acc[mi][ni], 0, 0, 0);
      af0 = afn;
    }
  }
  __syncthreads();

  // ---- O1 = relu(acc + b1) -> Dlds in place ----
  {
    const float2* b1k = b1 + k * 96;
#pragma unroll
    for (int mi = 0; mi < 6; ++mi) {
      int m0 = wm*96 + mi*16 + 4*g;
      int o0 = m0 >> 1;
      float2 ba = b1k[o0], bb = b1k[o0 + 1];
#pragma unroll
      for (int ni = 0; ni < 4; ++ni) {
        int n = wn*64 + ni*16 + lrow;
        f32x4 v = acc[mi][ni];
        u32 lo = pack_bf16(fmaxf(v[0] + ba.x, 0.f), fmaxf(v[1] + ba.y, 0.f));
        u32 hi = pack_bf16(fmaxf(v[2] + bb.x, 0.f), fmaxf(v[3] + bb.y, 0.f));
        int byte = (n*384 + m0*2) ^ dslot(n);
        *reinterpret_cast<uint2*>(smem + byte) = make_uint2(lo, hi);
      }
    }
  }
  __syncthreads();

  // ---- layer 2: acc = W2 x O1 ----
#pragma unroll
  for (int mi = 0; mi < 6; ++mi)
#pragma unroll
    for (int ni = 0; ni < 4; ++ni) acc[mi][ni] = (f32x4)0.f;
#pragma unroll
  for (int ks = 0; ks < 6; ++ks) {
    bf16x8 bf[4];
#pragma unroll
    for (int ni = 0; ni < 4; ++ni) {
      int n = wn*64 + ni*16 + lrow;
      bf[ni] = *reinterpret_cast<bf16x8*>(smem + ((n*384 + ks*64 + g*16) ^ dslot(n)));
    }
    bf16x8 af0 = W2v[(wm*96 + 0*16 + lrow)*24 + ks*4 + g];
#pragma unroll
    for (int mi = 0; mi < 6; ++mi) {
      bf16x8 afn;
      if (mi < 5) afn = W2v[(wm*96 + (mi+1)*16 + lrow)*24 + ks*4 + g];
#pragma unroll
      for (int ni = 0; ni < 4; ++ni)
        acc[mi][ni] = __builtin_amdgcn_mfma_f32_16x16x32_bf16(af0, bf[ni], acc[mi][ni], 0, 0, 0);
      af0 = afn;
    }
  }
  __syncthreads();

  // ---- epilogue: bias2 + softshrink -> Clds [c][n] (dword = c*258 + n) ----
  {
    u32* Clds = reinterpret_cast<u32*>(smem);
    const float2* b2k = b2 + k * 96;
#pragma unroll
    for (int mi = 0; mi < 6; ++mi) {
      int m0 = wm*96 + mi*16 + 4*g;
      int o0 = m0 >> 1;
      float2 ca = b2k[o0], cb = b2k[o0 + 1];
#pragma unroll
      for (int ni = 0; ni < 4; ++ni) {
        int n = wn*64 + ni*16 + lrow;
        f32x4 v = acc[mi][ni];
        Clds[o0*258 + n]       = pack_bf16(sshrink(v[0] + ca.x), sshrink(v[1] + ca.y));
        Clds[(o0 + 1)*258 + n] = pack_bf16(sshrink(v[2] + cb.x), sshrink(v[3] + cb.y));
      }
    }
  }
  __syncthreads();

  // ---- phase C: inverse FFT; stage 0-3 twiddles hoisted to regs, 4/5 closed ----
  {
    const u32* Clds = reinterpret_cast<const u32*>(smem);
    const float s = 1.f/256.f;
    float2 tw4[4], tw5[4];
    make_tw45(lane, tw4, tw5);
    float2 twh[4][4];
#pragma unroll
    for (int sx = 0; sx < 4; ++sx)
#pragma unroll
      for (int r = 0; r < 4; ++r) twh[sx][r] = Tlds[(sx*4+r)*64 + lane];
#pragma unroll
    for (int bt = 0; bt < 3; ++bt) {
      const int c0 = wave*12 + bt*4;
      float2 v4[4][4];
#pragma unroll
      for (int cc = 0; cc < 4; ++cc) {
        uint2 q0 = *reinterpret_cast<const uint2*>(Clds + (c0+cc)*258 + 4*lane);
        uint2 q1 = *reinterpret_cast<const uint2*>(Clds + (c0+cc)*258 + 4*lane + 2);
        v4[cc][0]=unpack_bf16(q0.x); v4[cc][1]=unpack_bf16(q0.y);
        v4[cc][2]=unpack_bf16(q1.x); v4[cc][3]=unpack_bf16(q1.y);
      }
#pragma unroll
      for (int cc = 0; cc < 4; ++cc) {
        float2* v = v4[cc];
        { float2 a=v[0]; v[0]=cadd(a,v[1]); v[1]=csub(a,v[1]);
          float2 c=v[2]; v[2]=cadd(c,v[3]); v[3]=csub(c,v[3]); }
        { v[3] = cmulj(v[3], 1.f);
          float2 a0=v[0]; v[0]=cadd(a0,v[2]); v[2]=csub(a0,v[2]);
          float2 a1=v[1]; v[1]=cadd(a1,v[3]); v[3]=csub(a1,v[3]); }
      }
      ditC_stage<1>(v4, tw5, lane);
      ditC_stage<2>(v4, tw4, lane);
      ditC_stage<4>(v4, twh[3], lane);
      ditC_stage<8>(v4, twh[2], lane);
      ditC_stage<16>(v4, twh[1], lane);
      ditC_stage<32>(v4, twh[0], lane);
#pragma unroll
      for (int cc = 0; cc < 4; ++cc) {
        uint4 o;
        o.x = pack_bf16(v4[cc][0].x*s, v4[cc][0].y*s);
        o.y = pack_bf16(v4[cc][1].x*s, v4[cc][1].y*s);
        o.z = pack_bf16(v4[cc][2].x*s, v4[cc][2].y*s);
        o.w = pack_bf16(v4[cc][3].x*s, v4[cc][3].y*s);
        *reinterpret_cast<uint4*>(F + colbase + (size_t)(c0+cc)*chstride + 4*lane) = o;
      }
    }
  }
}

// ---------------- Pass 5: row irfft (Hermitian ext), 2 rows per FFT, + bias ------
__global__ __launch_bounds__(256) void k_rowifft(const u32* __restrict__ F,
                                                 const float* __restrict__ x,
                                                 float* __restrict__ out) {
  __shared__ u32 stage[131*65];
  const int bc = blockIdx.x >> 2, hc = blockIdx.x & 3;
  const int tid = threadIdx.x, wave = tid >> 6, lane = tid & 63;
  Tw T = make_tw(lane, 1.f);
  for (int idx = tid; idx < 129*64; idx += 256) {
    int kw = idx >> 6, hl = idx & 63;
    stage[stage_row(kw)*65 + hl] = F[((size_t)bc*129 + kw)*256 + hc*64 + hl];
  }
  __syncthreads();

  const int L = brev6(lane);
#pragma unroll
  for (int rr = 0; rr < 8; ++rr) {
    const int hl0 = wave*16 + rr*2, hl1 = hl0 + 1;
    const float* xa = x + ((size_t)bc*256 + hc*64 + hl0) * 256;
    float xv0[4], xv1[4];
#pragma unroll
    for (int r=0;r<4;++r){ xv0[r]=xa[lane+64*r]; xv1[r]=xa[256+lane+64*r]; }
    float2 v[4];
#pragma unroll
    for (int r=0;r<4;++r) {
      int c = ((r&1)<<1) | (r>>1);
      int kw = 4*L + c;
      int src = (kw <= 128) ? kw : 256 - kw;
      float sg = (kw <= 128) ? 1.f : -1.f;
      int row = stage_row(src);
      float2 a = unpack_bf16(stage[row*65 + hl0]);
      float2 b = unpack_bf16(stage[row*65 + hl1]);
      a.y *= sg; b.y *= sg;
      if (kw == 0 || kw == 128) { a.y = 0.f; b.y = 0.f; }
      v[r] = make_float2(a.x - b.y, a.y + b.x);
    }
    fft256_dit(v, lane, T);
    float* oa = out + ((size_t)bc*256 + hc*64 + hl0) * 256;
#pragma unroll
    for (int r=0;r<4;++r) {
      int d = lane + 64*r;
      oa[d]       = v[r].x + xv0[r];
      oa[256 + d] = v[r].y + xv1[r];
    }
  }
}

extern "C" void kernel_launch(void* const* d_in, const int* in_sizes, int n_in,
                              void* d_out, int out_size, void* d_ws, size_t ws_size,
                              hipStream_t stream) {
  const float* x   = (const float*)d_in[0];
  const float2* w1 = (const float2*)d_in[1];
  const float2* b1 = (const float2*)d_in[2];
  const float2* w2 = (const float2*)d_in[3];
  const float2* b2 = (const float2*)d_in[4];
  float* out = (float*)d_out;
  u32* F = (u32*)d_ws;            // 1536*129*256*4 B ~ 203 MB
  u32* Wt = (u32*)d_out;          // d_out head as scratch; overwritten by k_rowifft

  (void)hipFuncSetAttribute(reinterpret_cast<const void*>(k_colmix),
                            hipFuncAttributeMaxDynamicSharedMemorySize, CM_LDS_BYTES);

  const int n_rows_blocks = 1536 * 4;
  const int n_cm_blocks   = 2 * 8 * 129;   // 2064 = 8 * 258

  k_prep_w<<<16, 256, 0, stream>>>(w1, w2, Wt);
  k_rowfft<<<n_rows_blocks, 256, 0, stream>>>(x, F);
  k_colmix<<<n_cm_blocks, 512, CM_LDS_BYTES, stream>>>(F, Wt, b1, b2);
  k_rowifft<<<n_rows_blocks, 256, 0, stream>>>(F, x, out);
}